// Round 4
// baseline (402.817 us; speedup 1.0000x reference)
//
#include <hip/hip_runtime.h>
#include <hip/hip_bf16.h>

typedef __attribute__((ext_vector_type(8))) short short8x;  // 8 bf16 = 4 VGPR
typedef __attribute__((ext_vector_type(4))) short short4x;  // 8B
typedef __attribute__((ext_vector_type(4))) float float4x;  // MFMA C/D
typedef __hip_bfloat16 bf16;

#define EPS_F 1.1920929e-07f
#define SCALE_F 0.07216878364870323f   // 192^-0.5

// flag semantics: 0 = primary inputs are bf16, 1 = primary inputs are fp32
__device__ inline float rdv(const void* p, size_t i, int f32) {
  return f32 ? ((const float*)p)[i] : __bfloat162float(((const bf16*)p)[i]);
}

__device__ inline int4 pack8(const float* s) {   // 8 fp32 -> 8 bf16 (RNE)
  unsigned short h[8];
#pragma unroll
  for (int t = 0; t < 8; t++) {
    bf16 b = __float2bfloat16(s[t]);
    __builtin_memcpy(&h[t], &b, 2);
  }
  int4 r;
  r.x = (int)((unsigned)h[0] | ((unsigned)h[1] << 16));
  r.y = (int)((unsigned)h[2] | ((unsigned)h[3] << 16));
  r.z = (int)((unsigned)h[4] | ((unsigned)h[5] << 16));
  r.w = (int)((unsigned)h[6] | ((unsigned)h[7] << 16));
  return r;
}

// async global->LDS, 16B per lane; LDS dest = wave-uniform base + lane*16
typedef __attribute__((address_space(1))) const unsigned int gu32;
typedef __attribute__((address_space(3))) unsigned int lu32;
__device__ __forceinline__ void gload16(const void* g, void* l) {
  __builtin_amdgcn_global_load_lds((gu32*)g, (lu32*)l, 16, 0, 0);
}

// -------- dtype detector --------
__global__ __launch_bounds__(256) void detect_dtype(const unsigned short* __restrict__ x,
                                                    int* __restrict__ flag) {
  int tid = threadIdx.x;
  int cnt = 0;
#pragma unroll
  for (int i = 0; i < 4; i++) {
    unsigned short u = x[tid * 4 + i];
    int e = (u >> 7) & 0xFF;
    cnt += (e >= 118 && e <= 130) ? 1 : 0;
  }
#pragma unroll
  for (int off = 1; off < 64; off <<= 1) cnt += __shfl_xor(cnt, off);
  __shared__ int red[4];
  if ((tid & 63) == 0) red[tid >> 6] = cnt;
  __syncthreads();
  if (tid == 0) flag[0] = ((red[0] + red[1] + red[2] + red[3]) > 768) ? 0 : 1;
}

__global__ __launch_bounds__(256) void sentinel_kernel(bf16* out, int n) {
  int i = blockIdx.x * 256 + threadIdx.x;
  if (i < n) out[i] = __float2bfloat16(1000.0f);
}

// ---------------- GEMM 128x128 body (round-7 logic + kbeg/kend/addbias) -----
template<int OMODE, bool A_DYN>
__device__ __forceinline__ void gemm128_body(
    const void* __restrict__ A, const void* __restrict__ W,
    const void* __restrict__ bias, void* __restrict__ Cout,
    int M, int N, int K, int f32in, int bx, int by,
    int kbeg, int kend, int addbias)
{
  __shared__ int4 As4[128 * 4];
  __shared__ int4 Bs4[128 * 4];
  const int tid = threadIdx.x, lane = tid & 63, wave = tid >> 6;
  const int grp = lane >> 4, l16 = lane & 15;
  const int m0 = bx * 128, n0 = by * 128;
  const int wm = (wave & 1) * 64, wn = (wave >> 1) * 64;
  float4x acc[4][4] = {};
  for (int k0 = kbeg; k0 < kend; k0 += 32) {
    if (!f32in) {
#pragma unroll
      for (int j = 0; j < 2; j++) {
        int row = wave * 32 + j * 16 + (lane >> 2);
        int cs = (lane & 3) ^ ((row >> 1) & 3);
        gload16((const bf16*)A + (size_t)(m0 + row) * K + k0 + cs * 8,
                &As4[(wave * 32 + j * 16) * 4]);
        gload16((const bf16*)W + (size_t)(n0 + row) * K + k0 + cs * 8,
                &Bs4[(wave * 32 + j * 16) * 4]);
      }
    } else {
#pragma unroll
      for (int i = 0; i < 2; i++) {
        int ch = tid + i * 256;
        int row = ch >> 2, c = ch & 3;
        int cs = c ^ ((row >> 1) & 3);
        size_t aoff = (size_t)(m0 + row) * K + k0 + cs * 8;
        size_t boff = (size_t)(n0 + row) * K + k0 + cs * 8;
        As4[row * 4 + c] = A_DYN ? pack8((const float*)A + aoff)
                                 : *(const int4*)((const bf16*)A + aoff);
        Bs4[row * 4 + c] = pack8((const float*)W + boff);
      }
    }
    __syncthreads();
    short8x af[4], bfr[4];
#pragma unroll
    for (int i = 0; i < 4; i++) {
      int ra = wm + i * 16 + l16;
      int rb = wn + i * 16 + l16;
      af[i]  = *(const short8x*)&As4[ra * 4 + (grp ^ ((ra >> 1) & 3))];
      bfr[i] = *(const short8x*)&Bs4[rb * 4 + (grp ^ ((rb >> 1) & 3))];
    }
#pragma unroll
    for (int i = 0; i < 4; i++)
#pragma unroll
      for (int j = 0; j < 4; j++)
        acc[i][j] = __builtin_amdgcn_mfma_f32_16x16x32_bf16(af[i], bfr[j], acc[i][j], 0, 0, 0);
    __syncthreads();
  }
#pragma unroll
  for (int j = 0; j < 4; j++) {
    int gn = n0 + wn + j * 16 + l16;
    float bv = addbias ? rdv(bias, gn, f32in) : 0.0f;
#pragma unroll
    for (int i = 0; i < 4; i++) {
      int gm0 = m0 + wm + i * 16 + grp * 4;
#pragma unroll
      for (int r = 0; r < 4; r++) {
        float v = acc[i][j][r] + bv;
        size_t idx = (size_t)(gm0 + r) * N + gn;
        if (OMODE == 0)      ((float*)Cout)[idx] = v;
        else if (OMODE == 1) ((bf16*)Cout)[idx] = __float2bfloat16(v);
        else {
          if (f32in) ((float*)Cout)[idx] = v;
          else       ((bf16*)Cout)[idx] = __float2bfloat16(v);
        }
      }
    }
  }
}

// q_b and kv_b in one dispatch: z=0 -> (qn,wq_b)->qbuf N=3072 (24 tiles);
// z=1 -> (kvn,wkv_b)->kvb N=4096 (32 tiles). Grid (16,32,2).
__global__ __launch_bounds__(256) void gemmB_dual(
    const void* __restrict__ A0, const void* __restrict__ A1,
    const void* __restrict__ W0, const void* __restrict__ W1,
    const void* __restrict__ b0, const void* __restrict__ b1,
    void* __restrict__ C0, void* __restrict__ C1,
    const int* __restrict__ flagp)
{
  const int z = blockIdx.z;
  if (z == 0 && blockIdx.y >= 24) return;
  const void* A = z ? A1 : A0;
  const void* W = z ? W1 : W0;
  const void* bias = z ? b1 : b0;
  void* C = z ? C1 : C0;
  const int N = z ? 4096 : 3072;
  gemm128_body<1, false>(A, W, bias, C, 2048, N, 512, flagp[0],
                         blockIdx.x, blockIdx.y, 0, 512, 1);
}

// wo split-K=2: z in {0,1} covers K-half, fp32 partials, bias in z==0.
// Grid (16,16,2) = 512 blocks (2/CU).
__global__ __launch_bounds__(256) void gemmWo_sk(
    const void* __restrict__ A, const void* __restrict__ W,
    const void* __restrict__ bias, float* __restrict__ part,
    const int* __restrict__ flagp)
{
  const int z = blockIdx.z;
  gemm128_body<0, false>(A, W, bias, part + (size_t)z * 2048 * 2048,
                         2048, 2048, 2048, flagp[0],
                         blockIdx.x, blockIdx.y, z * 1024, z * 1024 + 1024, z == 0);
}

// reduce: out = part0 + part1 (bias already in part0); out dtype per flag
__global__ __launch_bounds__(256) void reduce_out(
    const float* __restrict__ p0, const float* __restrict__ p1,
    void* __restrict__ out, const int* __restrict__ flagp)
{
  const int f32in = flagp[0];
  size_t i = ((size_t)blockIdx.x * 256 + threadIdx.x) * 4;
  float4 a = *(const float4*)(p0 + i);
  float4 b = *(const float4*)(p1 + i);
  a.x += b.x; a.y += b.y; a.z += b.z; a.w += b.w;
  if (f32in) {
    *(float4*)((float*)out + i) = a;
  } else {
    unsigned short h[4];
    bf16 t0 = __float2bfloat16(a.x); __builtin_memcpy(&h[0], &t0, 2);
    bf16 t1 = __float2bfloat16(a.y); __builtin_memcpy(&h[1], &t1, 2);
    bf16 t2 = __float2bfloat16(a.z); __builtin_memcpy(&h[2], &t2, 2);
    bf16 t3 = __float2bfloat16(a.w); __builtin_memcpy(&h[3], &t3, 2);
    int2 v;
    v.x = (int)((unsigned)h[0] | ((unsigned)h[1] << 16));
    v.y = (int)((unsigned)h[2] | ((unsigned)h[3] << 16));
    *(int2*)((bf16*)out + i) = v;
  }
}

// ---------------- GEMM 64x64 body (round-7 logic + kbeg/kend/addbias) -------
template<int OMODE, bool A_DYN>
__device__ __forceinline__ void gemm64_body(
    const void* __restrict__ A, const void* __restrict__ W,
    const void* __restrict__ bias, void* __restrict__ Cout,
    int M, int N, int K, int f32in, int bx, int by,
    int kbeg, int kend, int addbias)
{
  __shared__ int4 As4[64 * 4];
  __shared__ int4 Bs4[64 * 4];
  const int tid = threadIdx.x, lane = tid & 63, wave = tid >> 6;
  const int grp = lane >> 4, l16 = lane & 15;
  const int m0 = bx * 64, n0 = by * 64;
  const int wm = (wave & 1) * 32, wn = (wave >> 1) * 32;
  float4x acc[2][2] = {};
  for (int k0 = kbeg; k0 < kend; k0 += 32) {
    if (!f32in) {
      int row = wave * 16 + (lane >> 2);
      int cs = (lane & 3) ^ ((row >> 1) & 3);
      gload16((const bf16*)A + (size_t)(m0 + row) * K + k0 + cs * 8,
              &As4[wave * 16 * 4]);
      gload16((const bf16*)W + (size_t)(n0 + row) * K + k0 + cs * 8,
              &Bs4[wave * 16 * 4]);
    } else {
      int row = tid >> 2, c = tid & 3;
      int cs = c ^ ((row >> 1) & 3);
      size_t aoff = (size_t)(m0 + row) * K + k0 + cs * 8;
      size_t boff = (size_t)(n0 + row) * K + k0 + cs * 8;
      As4[row * 4 + c] = A_DYN ? pack8((const float*)A + aoff)
                               : *(const int4*)((const bf16*)A + aoff);
      Bs4[row * 4 + c] = pack8((const float*)W + boff);
    }
    __syncthreads();
    short8x af[2], bfr[2];
#pragma unroll
    for (int i = 0; i < 2; i++) {
      int ra = wm + i * 16 + l16;
      int rb = wn + i * 16 + l16;
      af[i]  = *(const short8x*)&As4[ra * 4 + (grp ^ ((ra >> 1) & 3))];
      bfr[i] = *(const short8x*)&Bs4[rb * 4 + (grp ^ ((rb >> 1) & 3))];
    }
#pragma unroll
    for (int i = 0; i < 2; i++)
#pragma unroll
      for (int j = 0; j < 2; j++)
        acc[i][j] = __builtin_amdgcn_mfma_f32_16x16x32_bf16(af[i], bfr[j], acc[i][j], 0, 0, 0);
    __syncthreads();
  }
#pragma unroll
  for (int j = 0; j < 2; j++) {
    int gn = n0 + wn + j * 16 + l16;
    float bv = addbias ? rdv(bias, gn, f32in) : 0.0f;
#pragma unroll
    for (int i = 0; i < 2; i++) {
      int gm0 = m0 + wm + i * 16 + grp * 4;
#pragma unroll
      for (int r = 0; r < 4; r++) {
        float v = acc[i][j][r] + bv;
        size_t idx = (size_t)(gm0 + r) * N + gn;
        if (OMODE == 0)      ((float*)Cout)[idx] = v;
        else if (OMODE == 1) ((bf16*)Cout)[idx] = __float2bfloat16(v);
        else {
          if (f32in) ((float*)Cout)[idx] = v;
          else       ((bf16*)Cout)[idx] = __float2bfloat16(v);
        }
      }
    }
  }
}

// q_a/kv_a projections, split-K=2, fused: grid (32,9,4);
// z = (mat<<1)|khalf; mat 0 -> q (N=512, skip y==8), mat 1 -> kv (N=576).
// fp32 partials C + khalf*M*N; bias in khalf==0.
__global__ __launch_bounds__(256) void gemmA_sk(
    const void* __restrict__ A,
    const void* __restrict__ W0, const void* __restrict__ W1,
    const void* __restrict__ b0, const void* __restrict__ b1,
    float* __restrict__ C0, float* __restrict__ C1,
    const int* __restrict__ flagp)
{
  const int z = blockIdx.z;
  const int mat = z >> 1, kh = z & 1;
  const int N = mat ? 576 : 512;
  if (blockIdx.y * 64 >= N) return;
  const void* W = mat ? W1 : W0;
  const void* bias = mat ? b1 : b0;
  float* C = (mat ? C1 : C0) + (size_t)kh * 2048 * N;
  gemm64_body<0, true>(A, W, bias, C, 2048, N, 2048, flagp[0],
                       blockIdx.x, blockIdx.y,
                       kh * 1024, kh * 1024 + 1024, kh == 0);
}

// ------ merged norms w/ fused split-K reduce: b<2048 -> q; else kv ----------
__global__ __launch_bounds__(256) void norms_merged(
    const float* __restrict__ q_a0, const float* __restrict__ q_a1,
    const float* __restrict__ kv_a0, const float* __restrict__ kv_a1,
    const void* __restrict__ qw, const void* __restrict__ kvw,
    const void* __restrict__ cosb, const void* __restrict__ sinb,
    bf16* __restrict__ qn, bf16* __restrict__ kvn, bf16* __restrict__ kpe,
    const int* __restrict__ flagp)
{
  const int f32in = flagp[0];
  const int b = blockIdx.x, tid = threadIdx.x;
  __shared__ float red[4];
  if (b < 2048) {
    const int s = b;
    size_t base = (size_t)s * 512;
    float v0 = q_a0[base + tid] + q_a1[base + tid];
    float v1 = q_a0[base + tid + 256] + q_a1[base + tid + 256];
    float ss = v0 * v0 + v1 * v1;
#pragma unroll
    for (int off = 1; off < 64; off <<= 1) ss += __shfl_xor(ss, off);
    if ((tid & 63) == 0) red[tid >> 6] = ss;
    __syncthreads();
    float tot = red[0] + red[1] + red[2] + red[3];
    float scale = rsqrtf(tot * (1.0f / 512.0f) + EPS_F);
    qn[base + tid]       = __float2bfloat16(v0 * scale * rdv(qw, tid, f32in));
    qn[base + tid + 256] = __float2bfloat16(v1 * scale * rdv(qw, tid + 256, f32in));
  } else {
    const int s = b - 2048;
    size_t base = (size_t)s * 576;
    float v0 = kv_a0[base + tid] + kv_a1[base + tid];
    float v1 = kv_a0[base + tid + 256] + kv_a1[base + tid + 256];
    float ss = v0 * v0 + v1 * v1;
#pragma unroll
    for (int off = 1; off < 64; off <<= 1) ss += __shfl_xor(ss, off);
    if ((tid & 63) == 0) red[tid >> 6] = ss;
    __syncthreads();
    float tot = red[0] + red[1] + red[2] + red[3];
    float scale = rsqrtf(tot * (1.0f / 512.0f) + EPS_F);
    kvn[(size_t)s * 512 + tid]       = __float2bfloat16(v0 * scale * rdv(kvw, tid, f32in));
    kvn[(size_t)s * 512 + tid + 256] = __float2bfloat16(v1 * scale * rdv(kvw, tid + 256, f32in));
    if (tid < 32) {
      float x0 = kv_a0[base + 512 + 2 * tid] + kv_a1[base + 512 + 2 * tid];
      float x1 = kv_a0[base + 512 + 2 * tid + 1] + kv_a1[base + 512 + 2 * tid + 1];
      float c  = rdv(cosb, (size_t)s * 32 + tid, f32in);
      float sn = rdv(sinb, (size_t)s * 32 + tid, f32in);
      kpe[s * 64 + 2 * tid]     = __float2bfloat16(x0 * c - x1 * sn);
      kpe[s * 64 + 2 * tid + 1] = __float2bfloat16(x0 * sn + x1 * c);
    }
  }
}

// ------ merged rope_q (b<2048) + build_vt (b>=2048, 512 blocks) -------------
__global__ __launch_bounds__(256) void rope_vt_merged(
    bf16* __restrict__ q, const void* __restrict__ cosb,
    const void* __restrict__ sinb, const bf16* __restrict__ kvb,
    bf16* __restrict__ Vt, const int* __restrict__ flagp)
{
  const int b = blockIdx.x, tid = threadIdx.x;
  __shared__ __align__(16) bf16 tile[64][136];
  if (b < 2048) {
    const int f32in = flagp[0];
    const int s = b;
#pragma unroll
    for (int it = 0; it < 2; it++) {
      int p = tid + it * 256;
      int hh = p >> 5, jj = p & 31;
      bf16* src = q + (size_t)s * 3072 + hh * 192 + 128 + 2 * jj;
      float x0 = __bfloat162float(src[0]);
      float x1 = __bfloat162float(src[1]);
      float c  = rdv(cosb, (size_t)s * 32 + jj, f32in);
      float sn = rdv(sinb, (size_t)s * 32 + jj, f32in);
      src[0] = __float2bfloat16(x0 * c - x1 * sn);
      src[1] = __float2bfloat16(x0 * sn + x1 * c);
    }
  } else {
    const int hb = b - 2048;                 // 0..511
    const int h = hb & 15;
    const int t0 = (hb >> 4) * 64;
#pragma unroll
    for (int i = 0; i < 4; i++) {
      int chunk = tid + i * 256;
      int row = chunk >> 4;
      int c8 = (chunk & 15) * 8;
      *(int4*)&tile[row][c8] =
          *(const int4*)(kvb + (size_t)(t0 + row) * 4096 + h * 256 + 128 + c8);
    }
    __syncthreads();
#pragma unroll
    for (int i = 0; i < 32; i++) {
      int idx = tid + i * 256;
      int d = idx >> 6;
      int t = idx & 63;
      Vt[((size_t)h * 128 + d) * 2048 + t0 + t] = tile[t][d];
    }
  }
}

// ---------------- flash attention v4: LDS double-buffer staged via
// global_load_lds (async DMA — compiler CANNOT sink it, unlike r1-r3's
// register prefetch). One barrier per KV tile. V read directly from global
// (Vt is L2/L3-resident; LDS stage was overhead + blocked the dbuf budget).
// K/kpe in linear LDS with XOR chunk-swizzle applied on the GLOBAL source
// and the matching XOR on the read side (both-sides involution).
// Softmax math identical to the verified round-0 path. ----------------------

// Stage one 64-row KV tile into buffer kb_: per wave 4 calls of 4 rows
// (K-nope, 128 bf16/row) + 2 calls of 8 rows (kpe, 64 bf16/row).
#define STAGE_TILE(kb_, T0_) { \
    const int rA = wave * 16; \
    _Pragma("unroll") \
    for (int j = 0; j < 4; j++) { \
      int row = rA + j * 4 + (lane >> 4); \
      int gch = (lane & 15) ^ (row & 7); \
      gload16(kvb + (size_t)((T0_) + row) * 4096 + h * 256 + gch * 8, \
              &KsN[kb_][(rA + j * 4) * 128]); \
    } \
    _Pragma("unroll") \
    for (int j = 0; j < 2; j++) { \
      int row = rA + j * 8 + (lane >> 3); \
      int gch = (lane & 7) ^ (row & 7); \
      gload16(kpe + (size_t)((T0_) + row) * 64 + gch * 8, \
              &KpB[kb_][(rA + j * 8) * 64]); \
    } }

__global__ __launch_bounds__(256, 2) void attn_kernel(
    const bf16* __restrict__ Q, const bf16* __restrict__ kvb,
    const bf16* __restrict__ kpe, const bf16* __restrict__ Vt,
    bf16* __restrict__ Out)
{
  __shared__ __align__(16) bf16 KsN[2][64 * 128];   // K nope, dbuf, linear
  __shared__ __align__(16) bf16 KpB[2][64 * 64];    // K rope, dbuf, linear
  __shared__ __align__(16) bf16 plds[4][16 * 68];
  const int b = blockIdx.x;
  const int h = b & 15;
  const int tt = (b >> 4) & 15;
  const int q0 = ((b >> 8) ? (31 - tt) : tt) * 64;
  const int tid = threadIdx.x;
  const int wave = tid >> 6;
  const int lane = tid & 63;
  const int grp = lane >> 4, l16 = lane & 15;
  const int qrt = q0 + wave * 16;

  const bf16* Qbase = Q + (size_t)(qrt + l16) * 3072 + h * 192;
  short8x qf[6];
#pragma unroll
  for (int c = 0; c < 6; c++)
    qf[c] = *(const short8x*)(Qbase + c * 32 + grp * 8);

  float m_run[4], l_run[4];
  float4x o_acc[8] = {};
#pragma unroll
  for (int r = 0; r < 4; r++) { m_run[r] = -__builtin_inff(); l_run[r] = 0.f; }
  bf16* pl = &plds[wave][0];
  // V row pointer for this lane: + n*16 rows (d) and + c*32 cols (t)
  const bf16* Vrow = Vt + (size_t)(h * 128 + l16) * 2048 + grp * 8;

  // prologue: stage tile 0 into buffer 0 (async; drained at first barrier)
  STAGE_TILE(0, 0);
  int kb = 0;

  for (int t0 = 0; t0 <= q0; t0 += 64) {
    const bool more = (t0 + 64 <= q0);
    __syncthreads();   // waitcnt(vmcnt 0) drain + barrier: buf[kb] ready
    // stage NEXT tile into the other buffer; in flight across full compute
    if (more) { STAGE_TILE(kb ^ 1, t0 + 64); }

    float4x sacc[4] = {};
    __builtin_amdgcn_s_setprio(1);
#pragma unroll
    for (int n = 0; n < 4; n++) {
      const int row = n * 16 + l16;
      const int sw = row & 7;
      const bf16* KbN = &KsN[kb][row * 128];
      const bf16* KbP = &KpB[kb][row * 64];
#pragma unroll
      for (int c = 0; c < 4; c++) {
        short8x kf = *(const short8x*)(KbN + (((c * 4 + grp) ^ sw) * 8));
        sacc[n] = __builtin_amdgcn_mfma_f32_16x16x32_bf16(qf[c], kf, sacc[n], 0, 0, 0);
      }
#pragma unroll
      for (int c = 0; c < 2; c++) {
        short8x kf = *(const short8x*)(KbP + (((c * 4 + grp) ^ sw) * 8));
        sacc[n] = __builtin_amdgcn_mfma_f32_16x16x32_bf16(qf[4 + c], kf, sacc[n], 0, 0, 0);
      }
    }
    __builtin_amdgcn_s_setprio(0);

    // softmax with defer-max (THR=8): skip rescale when max doesn't grow
    float p0[4][4], mxv[4];
    int grow = 0;
#pragma unroll
    for (int r = 0; r < 4; r++) {
      const int s_row = qrt + grp * 4 + r;
      float mx = -__builtin_inff();
#pragma unroll
      for (int n = 0; n < 4; n++) {
        int t = t0 + n * 16 + l16;
        float v = sacc[n][r] * SCALE_F;
        v = (t > s_row) ? -1.0e9f : v;
        p0[r][n] = v;
        mx = fmaxf(mx, v);
      }
      mx = fmaxf(mx, __shfl_xor(mx, 1));
      mx = fmaxf(mx, __shfl_xor(mx, 2));
      mx = fmaxf(mx, __shfl_xor(mx, 4));
      mx = fmaxf(mx, __shfl_xor(mx, 8));
      mxv[r] = mx;
      grow |= (mx > m_run[r] + 8.0f) ? 1 : 0;
    }
    if (__any(grow)) {
      float alpha[4];
#pragma unroll
      for (int r = 0; r < 4; r++) {
        float mn = fmaxf(m_run[r], mxv[r]);
        alpha[r] = __expf(m_run[r] - mn);
        m_run[r] = mn;
        l_run[r] *= alpha[r];
      }
#pragma unroll
      for (int n = 0; n < 8; n++)
#pragma unroll
        for (int r = 0; r < 4; r++)
          o_acc[n][r] *= alpha[r];
    }
    float pv[4][4];
#pragma unroll
    for (int r = 0; r < 4; r++) {
      float sum = 0.f;
#pragma unroll
      for (int n = 0; n < 4; n++) {
        float e = __expf(p0[r][n] - m_run[r]);
        pv[n][r] = e;
        sum += e;
      }
      sum += __shfl_xor(sum, 1);
      sum += __shfl_xor(sum, 2);
      sum += __shfl_xor(sum, 4);
      sum += __shfl_xor(sum, 8);
      l_run[r] += sum;
    }
#pragma unroll
    for (int n = 0; n < 4; n++)
#pragma unroll
      for (int r = 0; r < 4; r++)
        pl[(grp * 4 + r) * 68 + n * 16 + l16] = __float2bfloat16(pv[n][r]);

    __builtin_amdgcn_s_setprio(1);
#pragma unroll
    for (int c = 0; c < 2; c++) {
      union { short4x h4[2]; short8x v8; } pk;
      const bf16* pp = pl + l16 * 68 + c * 32 + grp * 8;
      pk.h4[0] = *(const short4x*)(pp);
      pk.h4[1] = *(const short4x*)(pp + 4);
#pragma unroll
      for (int n = 0; n < 8; n++) {
        // V direct from global (L2-resident Vt); coalesced 16B per lane
        short8x vf = *(const short8x*)(Vrow + (size_t)n * 16 * 2048 + t0 + c * 32);
        o_acc[n] = __builtin_amdgcn_mfma_f32_16x16x32_bf16(pk.v8, vf, o_acc[n], 0, 0, 0);
      }
    }
    __builtin_amdgcn_s_setprio(0);

    kb ^= 1;
  }
  float inv[4];
#pragma unroll
  for (int r = 0; r < 4; r++) inv[r] = 1.0f / l_run[r];
#pragma unroll
  for (int n = 0; n < 8; n++)
#pragma unroll
    for (int r = 0; r < 4; r++) {
      int s_row = qrt + grp * 4 + r;
      Out[(size_t)s_row * 2048 + h * 128 + n * 16 + l16] =
          __float2bfloat16(o_acc[n][r] * inv[r]);
    }
}

extern "C" void kernel_launch(void* const* d_in, const int* in_sizes, int n_in,
                              void* d_out, int out_size, void* d_ws, size_t ws_size,
                              hipStream_t stream) {
  const void* x        = d_in[0];
  const void* fcos     = d_in[2];
  const void* fsin     = d_in[3];
  const void* wq_a_w   = d_in[5];
  const void* wq_a_b   = d_in[6];
  const void* q_norm_w = d_in[7];
  const void* wq_b_w   = d_in[8];
  const void* wq_b_b   = d_in[9];
  const void* wkv_a_w  = d_in[10];
  const void* wkv_a_b  = d_in[11];
  const void* kv_norm_w= d_in[12];
  const void* wkv_b_w  = d_in[13];
  const void* wkv_b_b  = d_in[14];
  const void* wo_w     = d_in[15];
  const void* wo_b     = d_in[16];

  const size_t KB = 1024, MB = 1024 * 1024;
  if (ws_size < 46 * MB) {   // diagnostic: absmax ~1000 => ws too small
    sentinel_kernel<<<(out_size + 255) / 256, 256, 0, stream>>>((bf16*)d_out, out_size);
    return;
  }
  char* ws = (char*)d_ws;
  // Region plan, peak 44.5 MB. Persistent: kpe[0,0.25M) flag@0.25M
  //   qbuf[0.5,12.5) kvb[12.5,28.5) Vt[28.5,36.5) attnout[36.5,44.5).
  // Transients (time-disjoint with their hosts):
  //   kv_a0/1 [0.5,9.5)   in qbuf   (dead before gemmB writes qbuf)
  //   q_a0/1  [36.5,44.5) in attnout(dead before attn writes attnout)
  //   qn/kvn  [28.5,32.5) in Vt     (dead before rope_vt writes Vt)
  //   wpart   [0.5,32.5)  in qbuf+kvb+Vt (all dead after attn)
  bf16*  kpe    = (bf16*)(ws);
  int*   flag   = (int*)(ws + 256 * KB);
  bf16*  qbuf   = (bf16*)(ws + 512 * KB);
  bf16*  kvb    = (bf16*)(ws + 12 * MB + 512 * KB);
  bf16*  Vt     = (bf16*)(ws + 28 * MB + 512 * KB);
  bf16*  attnout= (bf16*)(ws + 36 * MB + 512 * KB);
  float* kv_a0  = (float*)(ws + 512 * KB);
  float* kv_a1  = (float*)(ws + 5 * MB);
  float* q_a0   = (float*)(ws + 36 * MB + 512 * KB);
  float* q_a1   = (float*)(ws + 40 * MB + 512 * KB);
  bf16*  qn     = (bf16*)(ws + 28 * MB + 512 * KB);
  bf16*  kvn    = (bf16*)(ws + 30 * MB + 512 * KB);
  float* wpart  = (float*)(ws + 512 * KB);

  dim3 blk(256);
  detect_dtype<<<1, blk, 0, stream>>>((const unsigned short*)x, flag);
  // q_a and kv_a projections, split-K=2, one dispatch (1088 active blocks)
  gemmA_sk<<<dim3(32, 9, 4), blk, 0, stream>>>(
      x, wq_a_w, wkv_a_w, wq_a_b, wkv_a_b, q_a0, kv_a0, flag);
  // both norms + split-K reduce fused (4096 blocks)
  norms_merged<<<4096, blk, 0, stream>>>(
      q_a0, q_a1, kv_a0, kv_a1, q_norm_w, kv_norm_w, fcos, fsin,
      qn, kvn, kpe, flag);
  // q_b and kv_b fused (896 active blocks, ~3.5/CU)
  gemmB_dual<<<dim3(16, 32, 2), blk, 0, stream>>>(
      qn, kvn, wq_b_w, wkv_b_w, wq_b_b, wkv_b_b, qbuf, kvb, flag);
  // rope on q (in place) + V transpose fused (2560 blocks)
  rope_vt_merged<<<2560, blk, 0, stream>>>(qbuf, fcos, fsin, kvb, Vt, flag);
  // attention (balanced flat-grid swizzle)
  attn_kernel<<<dim3(512), blk, 0, stream>>>(qbuf, kvb, kpe, Vt, attnout);
  // output projection split-K=2 (512 blocks) + reduce
  gemmWo_sk<<<dim3(16, 16, 2), blk, 0, stream>>>(attnout, wo_w, wo_b, wpart, flag);
  reduce_out<<<4096, blk, 0, stream>>>(wpart, wpart + (size_t)2048 * 2048, d_out, flag);
}

// Round 5
// 338.149 us; speedup vs baseline: 1.1912x; 1.1912x over previous
//
#include <hip/hip_runtime.h>
#include <hip/hip_bf16.h>

typedef __attribute__((ext_vector_type(8))) short short8x;  // 8 bf16 = 4 VGPR
typedef __attribute__((ext_vector_type(4))) short short4x;  // 8B
typedef __attribute__((ext_vector_type(4))) float float4x;  // MFMA C/D
typedef __hip_bfloat16 bf16;

#define EPS_F 1.1920929e-07f
#define SCALE_F 0.07216878364870323f   // 192^-0.5

// flag semantics: 0 = primary inputs are bf16, 1 = primary inputs are fp32
__device__ inline float rdv(const void* p, size_t i, int f32) {
  return f32 ? ((const float*)p)[i] : __bfloat162float(((const bf16*)p)[i]);
}

__device__ inline int4 pack8(const float* s) {   // 8 fp32 -> 8 bf16 (RNE)
  unsigned short h[8];
#pragma unroll
  for (int t = 0; t < 8; t++) {
    bf16 b = __float2bfloat16(s[t]);
    __builtin_memcpy(&h[t], &b, 2);
  }
  int4 r;
  r.x = (int)((unsigned)h[0] | ((unsigned)h[1] << 16));
  r.y = (int)((unsigned)h[2] | ((unsigned)h[3] << 16));
  r.z = (int)((unsigned)h[4] | ((unsigned)h[5] << 16));
  r.w = (int)((unsigned)h[6] | ((unsigned)h[7] << 16));
  return r;
}

// async global->LDS, 16B per lane; LDS dest = wave-uniform base + lane*16
typedef __attribute__((address_space(1))) const unsigned int gu32;
typedef __attribute__((address_space(3))) unsigned int lu32;
__device__ __forceinline__ void gload16(const void* g, void* l) {
  __builtin_amdgcn_global_load_lds((gu32*)g, (lu32*)l, 16, 0, 0);
}

// -------- dtype detector --------
__global__ __launch_bounds__(256) void detect_dtype(const unsigned short* __restrict__ x,
                                                    int* __restrict__ flag) {
  int tid = threadIdx.x;
  int cnt = 0;
#pragma unroll
  for (int i = 0; i < 4; i++) {
    unsigned short u = x[tid * 4 + i];
    int e = (u >> 7) & 0xFF;
    cnt += (e >= 118 && e <= 130) ? 1 : 0;
  }
#pragma unroll
  for (int off = 1; off < 64; off <<= 1) cnt += __shfl_xor(cnt, off);
  __shared__ int red[4];
  if ((tid & 63) == 0) red[tid >> 6] = cnt;
  __syncthreads();
  if (tid == 0) flag[0] = ((red[0] + red[1] + red[2] + red[3]) > 768) ? 0 : 1;
}

__global__ __launch_bounds__(256) void sentinel_kernel(bf16* out, int n) {
  int i = blockIdx.x * 256 + threadIdx.x;
  if (i < n) out[i] = __float2bfloat16(1000.0f);
}

// -------- bf16 conversion helpers (amortize the fp32 path ONCE) -------------
__device__ __forceinline__ void cvt8(const void* src, bf16* dst, size_t i, int f32) {
  if (f32) {
    float4 a = *(const float4*)((const float*)src + i);
    float4 b = *(const float4*)((const float*)src + i + 4);
    float s[8] = {a.x, a.y, a.z, a.w, b.x, b.y, b.z, b.w};
    *(int4*)(dst + i) = pack8(s);
  } else {
    *(int4*)(dst + i) = *(const int4*)((const bf16*)src + i);
  }
}

// convert x (2048 blks), wq_a (512), wkv_a (576), biases (1 blk). Grid 3137.
__global__ __launch_bounds__(256) void convert_in1(
    const void* __restrict__ x, const void* __restrict__ wqa,
    const void* __restrict__ wkva,
    const void* __restrict__ qab, const void* __restrict__ kvab,
    bf16* __restrict__ xb, bf16* __restrict__ wqab, bf16* __restrict__ wkvab,
    bf16* __restrict__ qabb, bf16* __restrict__ kvabb,
    const int* __restrict__ flagp)
{
  const int f32 = flagp[0];
  const int b = blockIdx.x, tid = threadIdx.x;
  if (b < 2048)       { size_t i = ((size_t)b * 256 + tid) * 8;          cvt8(x,    xb,    i, f32); }
  else if (b < 2560)  { size_t i = ((size_t)(b - 2048) * 256 + tid) * 8; cvt8(wqa,  wqab,  i, f32); }
  else if (b < 3136)  { size_t i = ((size_t)(b - 2560) * 256 + tid) * 8; cvt8(wkva, wkvab, i, f32); }
  else {
    for (int i = tid; i < 512; i += 256) qabb[i]  = __float2bfloat16(rdv(qab,  i, f32));
    for (int i = tid; i < 576; i += 256) kvabb[i] = __float2bfloat16(rdv(kvab, i, f32));
  }
}

// convert wq_b (768 blks), wkv_b (1024), biases (2). Grid 1794.
__global__ __launch_bounds__(256) void convert_in2(
    const void* __restrict__ wqb, const void* __restrict__ wkvb,
    const void* __restrict__ qbb, const void* __restrict__ kvbb,
    bf16* __restrict__ wqbb, bf16* __restrict__ wkvbb,
    bf16* __restrict__ qbbb, bf16* __restrict__ kvbbb,
    const int* __restrict__ flagp)
{
  const int f32 = flagp[0];
  const int b = blockIdx.x, tid = threadIdx.x;
  if (b < 768)        { size_t i = ((size_t)b * 256 + tid) * 8;          cvt8(wqb,  wqbb,  i, f32); }
  else if (b < 1792)  { size_t i = ((size_t)(b - 768) * 256 + tid) * 8;  cvt8(wkvb, wkvbb, i, f32); }
  else if (b == 1792) { for (int i = tid; i < 3072; i += 256) qbbb[i]  = __float2bfloat16(rdv(qbb,  i, f32)); }
  else                { for (int i = tid; i < 4096; i += 256) kvbbb[i] = __float2bfloat16(rdv(kvbb, i, f32)); }
}

// ---------------- GEMM 128x128 body (round-7 logic + kbeg/kend/addbias) -----
template<int OMODE, bool A_DYN>
__device__ __forceinline__ void gemm128_body(
    const void* __restrict__ A, const void* __restrict__ W,
    const void* __restrict__ bias, void* __restrict__ Cout,
    int M, int N, int K, int f32in, int bx, int by,
    int kbeg, int kend, int addbias)
{
  __shared__ int4 As4[128 * 4];
  __shared__ int4 Bs4[128 * 4];
  const int tid = threadIdx.x, lane = tid & 63, wave = tid >> 6;
  const int grp = lane >> 4, l16 = lane & 15;
  const int m0 = bx * 128, n0 = by * 128;
  const int wm = (wave & 1) * 64, wn = (wave >> 1) * 64;
  float4x acc[4][4] = {};
  for (int k0 = kbeg; k0 < kend; k0 += 32) {
    if (!f32in) {
#pragma unroll
      for (int j = 0; j < 2; j++) {
        int row = wave * 32 + j * 16 + (lane >> 2);
        int cs = (lane & 3) ^ ((row >> 1) & 3);
        gload16((const bf16*)A + (size_t)(m0 + row) * K + k0 + cs * 8,
                &As4[(wave * 32 + j * 16) * 4]);
        gload16((const bf16*)W + (size_t)(n0 + row) * K + k0 + cs * 8,
                &Bs4[(wave * 32 + j * 16) * 4]);
      }
    } else {
#pragma unroll
      for (int i = 0; i < 2; i++) {
        int ch = tid + i * 256;
        int row = ch >> 2, c = ch & 3;
        int cs = c ^ ((row >> 1) & 3);
        size_t aoff = (size_t)(m0 + row) * K + k0 + cs * 8;
        size_t boff = (size_t)(n0 + row) * K + k0 + cs * 8;
        As4[row * 4 + c] = A_DYN ? pack8((const float*)A + aoff)
                                 : *(const int4*)((const bf16*)A + aoff);
        Bs4[row * 4 + c] = pack8((const float*)W + boff);
      }
    }
    __syncthreads();
    short8x af[4], bfr[4];
#pragma unroll
    for (int i = 0; i < 4; i++) {
      int ra = wm + i * 16 + l16;
      int rb = wn + i * 16 + l16;
      af[i]  = *(const short8x*)&As4[ra * 4 + (grp ^ ((ra >> 1) & 3))];
      bfr[i] = *(const short8x*)&Bs4[rb * 4 + (grp ^ ((rb >> 1) & 3))];
    }
#pragma unroll
    for (int i = 0; i < 4; i++)
#pragma unroll
      for (int j = 0; j < 4; j++)
        acc[i][j] = __builtin_amdgcn_mfma_f32_16x16x32_bf16(af[i], bfr[j], acc[i][j], 0, 0, 0);
    __syncthreads();
  }
#pragma unroll
  for (int j = 0; j < 4; j++) {
    int gn = n0 + wn + j * 16 + l16;
    float bv = addbias ? rdv(bias, gn, f32in) : 0.0f;
#pragma unroll
    for (int i = 0; i < 4; i++) {
      int gm0 = m0 + wm + i * 16 + grp * 4;
#pragma unroll
      for (int r = 0; r < 4; r++) {
        float v = acc[i][j][r] + bv;
        size_t idx = (size_t)(gm0 + r) * N + gn;
        if (OMODE == 0)      ((float*)Cout)[idx] = v;
        else if (OMODE == 1) ((bf16*)Cout)[idx] = __float2bfloat16(v);
        else {
          if (f32in) ((float*)Cout)[idx] = v;
          else       ((bf16*)Cout)[idx] = __float2bfloat16(v);
        }
      }
    }
  }
}

// q_b and kv_b in one dispatch (bf16 fast path: weights pre-converted):
// z=0 -> (qn,wq_b)->qbuf N=3072 (24 tiles); z=1 -> (kvn,wkv_b)->kvb N=4096.
__global__ __launch_bounds__(256) void gemmB_dual(
    const void* __restrict__ A0, const void* __restrict__ A1,
    const void* __restrict__ W0, const void* __restrict__ W1,
    const void* __restrict__ b0, const void* __restrict__ b1,
    void* __restrict__ C0, void* __restrict__ C1)
{
  const int z = blockIdx.z;
  if (z == 0 && blockIdx.y >= 24) return;
  const void* A = z ? A1 : A0;
  const void* W = z ? W1 : W0;
  const void* bias = z ? b1 : b0;
  void* C = z ? C1 : C0;
  const int N = z ? 4096 : 3072;
  gemm128_body<1, false>(A, W, bias, C, 2048, N, 512, 0,
                         blockIdx.x, blockIdx.y, 0, 512, 1);
}

// wo split-K=2: z in {0,1} covers K-half, fp32 partials, bias in z==0.
// Grid (16,16,2) = 512 blocks (2/CU). (Stays on the flag path: no workspace
// window exists for an 8MB wo_bf16 during the wpart phase.)
__global__ __launch_bounds__(256) void gemmWo_sk(
    const void* __restrict__ A, const void* __restrict__ W,
    const void* __restrict__ bias, float* __restrict__ part,
    const int* __restrict__ flagp)
{
  const int z = blockIdx.z;
  gemm128_body<0, false>(A, W, bias, part + (size_t)z * 2048 * 2048,
                         2048, 2048, 2048, flagp[0],
                         blockIdx.x, blockIdx.y, z * 1024, z * 1024 + 1024, z == 0);
}

// reduce: out = part0 + part1 (bias already in part0); out dtype per flag
__global__ __launch_bounds__(256) void reduce_out(
    const float* __restrict__ p0, const float* __restrict__ p1,
    void* __restrict__ out, const int* __restrict__ flagp)
{
  const int f32in = flagp[0];
  size_t i = ((size_t)blockIdx.x * 256 + threadIdx.x) * 4;
  float4 a = *(const float4*)(p0 + i);
  float4 b = *(const float4*)(p1 + i);
  a.x += b.x; a.y += b.y; a.z += b.z; a.w += b.w;
  if (f32in) {
    *(float4*)((float*)out + i) = a;
  } else {
    unsigned short h[4];
    bf16 t0 = __float2bfloat16(a.x); __builtin_memcpy(&h[0], &t0, 2);
    bf16 t1 = __float2bfloat16(a.y); __builtin_memcpy(&h[1], &t1, 2);
    bf16 t2 = __float2bfloat16(a.z); __builtin_memcpy(&h[2], &t2, 2);
    bf16 t3 = __float2bfloat16(a.w); __builtin_memcpy(&h[3], &t3, 2);
    int2 v;
    v.x = (int)((unsigned)h[0] | ((unsigned)h[1] << 16));
    v.y = (int)((unsigned)h[2] | ((unsigned)h[3] << 16));
    *(int2*)((bf16*)out + i) = v;
  }
}

// ---------------- GEMM 64x64 body (round-7 logic + kbeg/kend/addbias) -------
template<int OMODE, bool A_DYN>
__device__ __forceinline__ void gemm64_body(
    const void* __restrict__ A, const void* __restrict__ W,
    const void* __restrict__ bias, void* __restrict__ Cout,
    int M, int N, int K, int f32in, int bx, int by,
    int kbeg, int kend, int addbias)
{
  __shared__ int4 As4[64 * 4];
  __shared__ int4 Bs4[64 * 4];
  const int tid = threadIdx.x, lane = tid & 63, wave = tid >> 6;
  const int grp = lane >> 4, l16 = lane & 15;
  const int m0 = bx * 64, n0 = by * 64;
  const int wm = (wave & 1) * 32, wn = (wave >> 1) * 32;
  float4x acc[2][2] = {};
  for (int k0 = kbeg; k0 < kend; k0 += 32) {
    if (!f32in) {
      int row = wave * 16 + (lane >> 2);
      int cs = (lane & 3) ^ ((row >> 1) & 3);
      gload16((const bf16*)A + (size_t)(m0 + row) * K + k0 + cs * 8,
              &As4[wave * 16 * 4]);
      gload16((const bf16*)W + (size_t)(n0 + row) * K + k0 + cs * 8,
              &Bs4[wave * 16 * 4]);
    } else {
      int row = tid >> 2, c = tid & 3;
      int cs = c ^ ((row >> 1) & 3);
      size_t aoff = (size_t)(m0 + row) * K + k0 + cs * 8;
      size_t boff = (size_t)(n0 + row) * K + k0 + cs * 8;
      As4[row * 4 + c] = A_DYN ? pack8((const float*)A + aoff)
                               : *(const int4*)((const bf16*)A + aoff);
      Bs4[row * 4 + c] = pack8((const float*)W + boff);
    }
    __syncthreads();
    short8x af[2], bfr[2];
#pragma unroll
    for (int i = 0; i < 2; i++) {
      int ra = wm + i * 16 + l16;
      int rb = wn + i * 16 + l16;
      af[i]  = *(const short8x*)&As4[ra * 4 + (grp ^ ((ra >> 1) & 3))];
      bfr[i] = *(const short8x*)&Bs4[rb * 4 + (grp ^ ((rb >> 1) & 3))];
    }
#pragma unroll
    for (int i = 0; i < 2; i++)
#pragma unroll
      for (int j = 0; j < 2; j++)
        acc[i][j] = __builtin_amdgcn_mfma_f32_16x16x32_bf16(af[i], bfr[j], acc[i][j], 0, 0, 0);
    __syncthreads();
  }
#pragma unroll
  for (int j = 0; j < 2; j++) {
    int gn = n0 + wn + j * 16 + l16;
    float bv = addbias ? rdv(bias, gn, f32in) : 0.0f;
#pragma unroll
    for (int i = 0; i < 2; i++) {
      int gm0 = m0 + wm + i * 16 + grp * 4;
#pragma unroll
      for (int r = 0; r < 4; r++) {
        float v = acc[i][j][r] + bv;
        size_t idx = (size_t)(gm0 + r) * N + gn;
        if (OMODE == 0)      ((float*)Cout)[idx] = v;
        else if (OMODE == 1) ((bf16*)Cout)[idx] = __float2bfloat16(v);
        else {
          if (f32in) ((float*)Cout)[idx] = v;
          else       ((bf16*)Cout)[idx] = __float2bfloat16(v);
        }
      }
    }
  }
}

// q_a/kv_a projections on pre-converted bf16 inputs (fast gload16 path),
// split-K=2, fused: grid (32,9,4); z = (mat<<1)|khalf.
__global__ __launch_bounds__(256) void gemmA_sk(
    const void* __restrict__ A,
    const void* __restrict__ W0, const void* __restrict__ W1,
    const void* __restrict__ b0, const void* __restrict__ b1,
    float* __restrict__ C0, float* __restrict__ C1)
{
  const int z = blockIdx.z;
  const int mat = z >> 1, kh = z & 1;
  const int N = mat ? 576 : 512;
  if (blockIdx.y * 64 >= N) return;
  const void* W = mat ? W1 : W0;
  const void* bias = mat ? b1 : b0;
  float* C = (mat ? C1 : C0) + (size_t)kh * 2048 * N;
  gemm64_body<0, false>(A, W, bias, C, 2048, N, 2048, 0,
                        blockIdx.x, blockIdx.y,
                        kh * 1024, kh * 1024 + 1024, kh == 0);
}

// ------ merged norms w/ fused split-K reduce: b<2048 -> q; else kv ----------
__global__ __launch_bounds__(256) void norms_merged(
    const float* __restrict__ q_a0, const float* __restrict__ q_a1,
    const float* __restrict__ kv_a0, const float* __restrict__ kv_a1,
    const void* __restrict__ qw, const void* __restrict__ kvw,
    const void* __restrict__ cosb, const void* __restrict__ sinb,
    bf16* __restrict__ qn, bf16* __restrict__ kvn, bf16* __restrict__ kpe,
    const int* __restrict__ flagp)
{
  const int f32in = flagp[0];
  const int b = blockIdx.x, tid = threadIdx.x;
  __shared__ float red[4];
  if (b < 2048) {
    const int s = b;
    size_t base = (size_t)s * 512;
    float v0 = q_a0[base + tid] + q_a1[base + tid];
    float v1 = q_a0[base + tid + 256] + q_a1[base + tid + 256];
    float ss = v0 * v0 + v1 * v1;
#pragma unroll
    for (int off = 1; off < 64; off <<= 1) ss += __shfl_xor(ss, off);
    if ((tid & 63) == 0) red[tid >> 6] = ss;
    __syncthreads();
    float tot = red[0] + red[1] + red[2] + red[3];
    float scale = rsqrtf(tot * (1.0f / 512.0f) + EPS_F);
    qn[base + tid]       = __float2bfloat16(v0 * scale * rdv(qw, tid, f32in));
    qn[base + tid + 256] = __float2bfloat16(v1 * scale * rdv(qw, tid + 256, f32in));
  } else {
    const int s = b - 2048;
    size_t base = (size_t)s * 576;
    float v0 = kv_a0[base + tid] + kv_a1[base + tid];
    float v1 = kv_a0[base + tid + 256] + kv_a1[base + tid + 256];
    float ss = v0 * v0 + v1 * v1;
#pragma unroll
    for (int off = 1; off < 64; off <<= 1) ss += __shfl_xor(ss, off);
    if ((tid & 63) == 0) red[tid >> 6] = ss;
    __syncthreads();
    float tot = red[0] + red[1] + red[2] + red[3];
    float scale = rsqrtf(tot * (1.0f / 512.0f) + EPS_F);
    kvn[(size_t)s * 512 + tid]       = __float2bfloat16(v0 * scale * rdv(kvw, tid, f32in));
    kvn[(size_t)s * 512 + tid + 256] = __float2bfloat16(v1 * scale * rdv(kvw, tid + 256, f32in));
    if (tid < 32) {
      float x0 = kv_a0[base + 512 + 2 * tid] + kv_a1[base + 512 + 2 * tid];
      float x1 = kv_a0[base + 512 + 2 * tid + 1] + kv_a1[base + 512 + 2 * tid + 1];
      float c  = rdv(cosb, (size_t)s * 32 + tid, f32in);
      float sn = rdv(sinb, (size_t)s * 32 + tid, f32in);
      kpe[s * 64 + 2 * tid]     = __float2bfloat16(x0 * c - x1 * sn);
      kpe[s * 64 + 2 * tid + 1] = __float2bfloat16(x0 * sn + x1 * c);
    }
  }
}

// ------ merged rope_q (b<2048) + build_vt (b>=2048, 512 blocks) -------------
__global__ __launch_bounds__(256) void rope_vt_merged(
    bf16* __restrict__ q, const void* __restrict__ cosb,
    const void* __restrict__ sinb, const bf16* __restrict__ kvb,
    bf16* __restrict__ Vt, const int* __restrict__ flagp)
{
  const int b = blockIdx.x, tid = threadIdx.x;
  __shared__ __align__(16) bf16 tile[64][136];
  if (b < 2048) {
    const int f32in = flagp[0];
    const int s = b;
#pragma unroll
    for (int it = 0; it < 2; it++) {
      int p = tid + it * 256;
      int hh = p >> 5, jj = p & 31;
      bf16* src = q + (size_t)s * 3072 + hh * 192 + 128 + 2 * jj;
      float x0 = __bfloat162float(src[0]);
      float x1 = __bfloat162float(src[1]);
      float c  = rdv(cosb, (size_t)s * 32 + jj, f32in);
      float sn = rdv(sinb, (size_t)s * 32 + jj, f32in);
      src[0] = __float2bfloat16(x0 * c - x1 * sn);
      src[1] = __float2bfloat16(x0 * sn + x1 * c);
    }
  } else {
    const int hb = b - 2048;                 // 0..511
    const int h = hb & 15;
    const int t0 = (hb >> 4) * 64;
#pragma unroll
    for (int i = 0; i < 4; i++) {
      int chunk = tid + i * 256;
      int row = chunk >> 4;
      int c8 = (chunk & 15) * 8;
      *(int4*)&tile[row][c8] =
          *(const int4*)(kvb + (size_t)(t0 + row) * 4096 + h * 256 + 128 + c8);
    }
    __syncthreads();
#pragma unroll
    for (int i = 0; i < 32; i++) {
      int idx = tid + i * 256;
      int d = idx >> 6;
      int t = idx & 63;
      Vt[((size_t)h * 128 + d) * 2048 + t0 + t] = tile[t][d];
    }
  }
}

// ---------------- flash attention (round-0 exact, the verified 81.5 µs
// version; r1-r4 restructurings all regressed and are reverted) --------------
__global__ __launch_bounds__(256) void attn_kernel(
    const bf16* __restrict__ Q, const bf16* __restrict__ kvb,
    const bf16* __restrict__ kpe, const bf16* __restrict__ Vt,
    bf16* __restrict__ Out)
{
  __shared__ __align__(16) bf16 Ks[64 * 200];
  __shared__ __align__(16) bf16 Vs[128 * 72];
  __shared__ __align__(16) bf16 plds[4][16 * 68];
  const int b = blockIdx.x;
  const int h = b & 15;
  const int tt = (b >> 4) & 15;
  const int q0 = ((b >> 8) ? (31 - tt) : tt) * 64;
  const int tid = threadIdx.x;
  const int wave = tid >> 6;
  const int lane = tid & 63;
  const int grp = lane >> 4, l16 = lane & 15;
  const int qrt = q0 + wave * 16;
  const bf16* Qbase = Q + (size_t)(qrt + l16) * 3072 + h * 192;
  short8x qf[6];
#pragma unroll
  for (int c = 0; c < 6; c++)
    qf[c] = *(const short8x*)(Qbase + c * 32 + grp * 8);
  float m_run[4], l_run[4];
  float4x o_acc[8] = {};
#pragma unroll
  for (int r = 0; r < 4; r++) { m_run[r] = -__builtin_inff(); l_run[r] = 0.f; }
  bf16* pl = &plds[wave][0];
  for (int t0 = 0; t0 <= q0; t0 += 64) {
#pragma unroll
    for (int i = 0; i < 4; i++) {
      int ch = tid + i * 256;
      int row = ch >> 4, c = ch & 15;
      *(int4*)&Ks[row * 200 + c * 8] =
          *(const int4*)(kvb + (size_t)(t0 + row) * 4096 + h * 256 + c * 8);
    }
#pragma unroll
    for (int i = 0; i < 2; i++) {
      int ch = tid + i * 256;
      int row = ch >> 3, c = ch & 7;
      *(int4*)&Ks[row * 200 + 128 + c * 8] =
          *(const int4*)(kpe + (size_t)(t0 + row) * 64 + c * 8);
    }
#pragma unroll
    for (int i = 0; i < 4; i++) {
      int ch = tid + i * 256;
      int row = ch >> 3, c = ch & 7;
      *(int4*)&Vs[row * 72 + c * 8] =
          *(const int4*)(Vt + ((size_t)h * 128 + row) * 2048 + t0 + c * 8);
    }
    __syncthreads();
    float4x sacc[4] = {};
#pragma unroll
    for (int n = 0; n < 4; n++) {
      const bf16* Kb = &Ks[(n * 16 + l16) * 200 + grp * 8];
#pragma unroll
      for (int c = 0; c < 6; c++) {
        short8x kf = *(const short8x*)(Kb + c * 32);
        sacc[n] = __builtin_amdgcn_mfma_f32_16x16x32_bf16(qf[c], kf, sacc[n], 0, 0, 0);
      }
    }
    float pv[4][4], alpha[4];
#pragma unroll
    for (int r = 0; r < 4; r++) {
      const int s_row = qrt + grp * 4 + r;
      float p0[4];
      float mx = -__builtin_inff();
#pragma unroll
      for (int n = 0; n < 4; n++) {
        int t = t0 + n * 16 + l16;
        float v = sacc[n][r] * SCALE_F;
        v = (t > s_row) ? -1.0e9f : v;
        p0[n] = v;
        mx = fmaxf(mx, v);
      }
      mx = fmaxf(mx, __shfl_xor(mx, 1));
      mx = fmaxf(mx, __shfl_xor(mx, 2));
      mx = fmaxf(mx, __shfl_xor(mx, 4));
      mx = fmaxf(mx, __shfl_xor(mx, 8));
      float m_new = fmaxf(m_run[r], mx);
      float a = __expf(m_run[r] - m_new);
      m_run[r] = m_new;
      float sum = 0.f;
#pragma unroll
      for (int n = 0; n < 4; n++) {
        float e = __expf(p0[n] - m_new);
        pv[n][r] = e;
        sum += e;
      }
      sum += __shfl_xor(sum, 1);
      sum += __shfl_xor(sum, 2);
      sum += __shfl_xor(sum, 4);
      sum += __shfl_xor(sum, 8);
      l_run[r] = l_run[r] * a + sum;
      alpha[r] = a;
    }
#pragma unroll
    for (int n = 0; n < 8; n++)
#pragma unroll
      for (int r = 0; r < 4; r++)
        o_acc[n][r] *= alpha[r];
#pragma unroll
    for (int n = 0; n < 4; n++)
#pragma unroll
      for (int r = 0; r < 4; r++)
        pl[(grp * 4 + r) * 68 + n * 16 + l16] = __float2bfloat16(pv[n][r]);
#pragma unroll
    for (int c = 0; c < 2; c++) {
      union { short4x h4[2]; short8x v8; } pk;
      const bf16* pp = pl + l16 * 68 + c * 32 + grp * 8;
      pk.h4[0] = *(const short4x*)(pp);
      pk.h4[1] = *(const short4x*)(pp + 4);
#pragma unroll
      for (int n = 0; n < 8; n++) {
        short8x vf = *(const short8x*)&Vs[(size_t)(n * 16 + l16) * 72 + c * 32 + grp * 8];
        o_acc[n] = __builtin_amdgcn_mfma_f32_16x16x32_bf16(pk.v8, vf, o_acc[n], 0, 0, 0);
      }
    }
    __syncthreads();
  }
  float inv[4];
#pragma unroll
  for (int r = 0; r < 4; r++) inv[r] = 1.0f / l_run[r];
#pragma unroll
  for (int n = 0; n < 8; n++)
#pragma unroll
    for (int r = 0; r < 4; r++) {
      int s_row = qrt + grp * 4 + r;
      Out[(size_t)s_row * 2048 + h * 128 + n * 16 + l16] =
          __float2bfloat16(o_acc[n][r] * inv[r]);
    }
}

extern "C" void kernel_launch(void* const* d_in, const int* in_sizes, int n_in,
                              void* d_out, int out_size, void* d_ws, size_t ws_size,
                              hipStream_t stream) {
  const void* x        = d_in[0];
  const void* fcos     = d_in[2];
  const void* fsin     = d_in[3];
  const void* wq_a_w   = d_in[5];
  const void* wq_a_b   = d_in[6];
  const void* q_norm_w = d_in[7];
  const void* wq_b_w   = d_in[8];
  const void* wq_b_b   = d_in[9];
  const void* wkv_a_w  = d_in[10];
  const void* wkv_a_b  = d_in[11];
  const void* kv_norm_w= d_in[12];
  const void* wkv_b_w  = d_in[13];
  const void* wkv_b_b  = d_in[14];
  const void* wo_w     = d_in[15];
  const void* wo_b     = d_in[16];

  const size_t KB = 1024, MB = 1024 * 1024;
  if (ws_size < 46 * MB) {   // diagnostic: absmax ~1000 => ws too small
    sentinel_kernel<<<(out_size + 255) / 256, 256, 0, stream>>>((bf16*)d_out, out_size);
    return;
  }
  char* ws = (char*)d_ws;
  // Region plan, peak 44.5 MB. Persistent: kpe[0,0.25M) flag@0.25M
  //   qbuf[0.5,12.5) kvb[12.5,28.5) Vt[28.5,36.5) attnout[36.5,44.5).
  // Transients (time-disjoint with their hosts):
  //   kv_a0/1 [0.5,9.5)   in qbuf    (dead before gemmB writes qbuf)
  //   q_a0/1  [36.5,44.5) in attnout (dead before convert_in2)
  //   xb/wqab/wkvab/biasA [12.5,25.1) in kvb (dead before gemmB writes kvb)
  //   wqbb/wkvbb/biasB [36.5,43.8) in attnout (written after norms; dead
  //                                  before attn writes attnout)
  //   qn/kvn  [28.5,32.5) in Vt      (dead before rope_vt writes Vt)
  //   wpart   [0.5,32.5)  in qbuf+kvb+Vt (all dead after attn)
  bf16*  kpe    = (bf16*)(ws);
  int*   flag   = (int*)(ws + 256 * KB);
  bf16*  qbuf   = (bf16*)(ws + 512 * KB);
  bf16*  kvb    = (bf16*)(ws + 12 * MB + 512 * KB);
  bf16*  Vt     = (bf16*)(ws + 28 * MB + 512 * KB);
  bf16*  attnout= (bf16*)(ws + 36 * MB + 512 * KB);
  float* kv_a0  = (float*)(ws + 512 * KB);
  float* kv_a1  = (float*)(ws + 5 * MB);
  float* q_a0   = (float*)(ws + 36 * MB + 512 * KB);
  float* q_a1   = (float*)(ws + 40 * MB + 512 * KB);
  bf16*  qn     = (bf16*)(ws + 28 * MB + 512 * KB);
  bf16*  kvn    = (bf16*)(ws + 30 * MB + 512 * KB);
  float* wpart  = (float*)(ws + 512 * KB);
  // bf16 conversion targets
  bf16*  xb     = (bf16*)(ws + 12 * MB + 512 * KB);   // 8MB   [12.5,20.5)
  bf16*  wqab   = (bf16*)(ws + 20 * MB + 512 * KB);   // 2MB   [20.5,22.5)
  bf16*  wkvab  = (bf16*)(ws + 22 * MB + 512 * KB);   // 2.25M [22.5,24.75)
  bf16*  qabb   = (bf16*)(ws + 25 * MB);              // 1KB
  bf16*  kvabb  = (bf16*)(ws + 25 * MB + 64 * KB);    // 1.2KB
  bf16*  wqbb   = (bf16*)(ws + 36 * MB + 512 * KB);   // 3MB   [36.5,39.5)
  bf16*  wkvbb  = (bf16*)(ws + 39 * MB + 512 * KB);   // 4MB   [39.5,43.5)
  bf16*  qbbb   = (bf16*)(ws + 43 * MB + 512 * KB);   // 6KB
  bf16*  kvbbb  = (bf16*)(ws + 43 * MB + 768 * KB);   // 8KB

  dim3 blk(256);
  detect_dtype<<<1, blk, 0, stream>>>((const unsigned short*)x, flag);
  // amortized fp32->bf16: x + A-stage weights/biases (into kvb region)
  convert_in1<<<3137, blk, 0, stream>>>(
      x, wq_a_w, wkv_a_w, wq_a_b, wkv_a_b, xb, wqab, wkvab, qabb, kvabb, flag);
  // q_a and kv_a projections on bf16 fast path, split-K=2
  gemmA_sk<<<dim3(32, 9, 4), blk, 0, stream>>>(
      xb, wqab, wkvab, qabb, kvabb, q_a0, kv_a0);
  // both norms + split-K reduce fused (4096 blocks)
  norms_merged<<<4096, blk, 0, stream>>>(
      q_a0, q_a1, kv_a0, kv_a1, q_norm_w, kv_norm_w, fcos, fsin,
      qn, kvn, kpe, flag);
  // B-stage weights/biases -> bf16 (into attnout region; q_a now dead)
  convert_in2<<<1794, blk, 0, stream>>>(
      wq_b_w, wkv_b_w, wq_b_b, wkv_b_b, wqbb, wkvbb, qbbb, kvbbb, flag);
  // q_b and kv_b fused on bf16 fast path (896 active blocks)
  gemmB_dual<<<dim3(16, 32, 2), blk, 0, stream>>>(
      qn, kvn, wqbb, wkvbb, qbbb, kvbbb, qbuf, kvb);
  // rope on q (in place) + V transpose fused (2560 blocks)
  rope_vt_merged<<<2560, blk, 0, stream>>>(qbuf, fcos, fsin, kvb, Vt, flag);
  // attention (round-0 exact)
  attn_kernel<<<dim3(512), blk, 0, stream>>>(qbuf, kvb, kpe, Vt, attnout);
  // output projection split-K=2 (512 blocks) + reduce
  gemmWo_sk<<<dim3(16, 16, 2), blk, 0, stream>>>(attnout, wo_w, wo_b, wpart, flag);
  reduce_out<<<4096, blk, 0, stream>>>(wpart, wpart + (size_t)2048 * 2048, d_out, flag);
}

// Round 6
// 327.909 us; speedup vs baseline: 1.2284x; 1.0312x over previous
//
#include <hip/hip_runtime.h>
#include <hip/hip_bf16.h>

typedef __attribute__((ext_vector_type(8))) short short8x;  // 8 bf16 = 4 VGPR
typedef __attribute__((ext_vector_type(4))) short short4x;  // 8B
typedef __attribute__((ext_vector_type(4))) float float4x;  // MFMA C/D
typedef __hip_bfloat16 bf16;

#define EPS_F 1.1920929e-07f
#define SCALE_F 0.07216878364870323f   // 192^-0.5

// flag semantics: 0 = primary inputs are bf16, 1 = primary inputs are fp32
__device__ inline float rdv(const void* p, size_t i, int f32) {
  return f32 ? ((const float*)p)[i] : __bfloat162float(((const bf16*)p)[i]);
}

__device__ inline int4 pack8(const float* s) {   // 8 fp32 -> 8 bf16 (RNE)
  unsigned short h[8];
#pragma unroll
  for (int t = 0; t < 8; t++) {
    bf16 b = __float2bfloat16(s[t]);
    __builtin_memcpy(&h[t], &b, 2);
  }
  int4 r;
  r.x = (int)((unsigned)h[0] | ((unsigned)h[1] << 16));
  r.y = (int)((unsigned)h[2] | ((unsigned)h[3] << 16));
  r.z = (int)((unsigned)h[4] | ((unsigned)h[5] << 16));
  r.w = (int)((unsigned)h[6] | ((unsigned)h[7] << 16));
  return r;
}

// async global->LDS, 16B per lane; LDS dest = wave-uniform base + lane*16
typedef __attribute__((address_space(1))) const unsigned int gu32;
typedef __attribute__((address_space(3))) unsigned int lu32;
__device__ __forceinline__ void gload16(const void* g, void* l) {
  __builtin_amdgcn_global_load_lds((gu32*)g, (lu32*)l, 16, 0, 0);
}

// -------- dtype detector --------
__global__ __launch_bounds__(256) void detect_dtype(const unsigned short* __restrict__ x,
                                                    int* __restrict__ flag) {
  int tid = threadIdx.x;
  int cnt = 0;
#pragma unroll
  for (int i = 0; i < 4; i++) {
    unsigned short u = x[tid * 4 + i];
    int e = (u >> 7) & 0xFF;
    cnt += (e >= 118 && e <= 130) ? 1 : 0;
  }
#pragma unroll
  for (int off = 1; off < 64; off <<= 1) cnt += __shfl_xor(cnt, off);
  __shared__ int red[4];
  if ((tid & 63) == 0) red[tid >> 6] = cnt;
  __syncthreads();
  if (tid == 0) flag[0] = ((red[0] + red[1] + red[2] + red[3]) > 768) ? 0 : 1;
}

__global__ __launch_bounds__(256) void sentinel_kernel(bf16* out, int n) {
  int i = blockIdx.x * 256 + threadIdx.x;
  if (i < n) out[i] = __float2bfloat16(1000.0f);
}

// -------- bf16 conversion helpers (amortize the fp32 path ONCE) -------------
__device__ __forceinline__ void cvt8(const void* src, bf16* dst, size_t i, int f32) {
  if (f32) {
    float4 a = *(const float4*)((const float*)src + i);
    float4 b = *(const float4*)((const float*)src + i + 4);
    float s[8] = {a.x, a.y, a.z, a.w, b.x, b.y, b.z, b.w};
    *(int4*)(dst + i) = pack8(s);
  } else {
    *(int4*)(dst + i) = *(const int4*)((const bf16*)src + i);
  }
}

// convert x (2048 blks), wq_a (512), wkv_a (576), biases (1 blk). Grid 3137.
__global__ __launch_bounds__(256) void convert_in1(
    const void* __restrict__ x, const void* __restrict__ wqa,
    const void* __restrict__ wkva,
    const void* __restrict__ qab, const void* __restrict__ kvab,
    bf16* __restrict__ xb, bf16* __restrict__ wqab, bf16* __restrict__ wkvab,
    bf16* __restrict__ qabb, bf16* __restrict__ kvabb,
    const int* __restrict__ flagp)
{
  const int f32 = flagp[0];
  const int b = blockIdx.x, tid = threadIdx.x;
  if (b < 2048)       { size_t i = ((size_t)b * 256 + tid) * 8;          cvt8(x,    xb,    i, f32); }
  else if (b < 2560)  { size_t i = ((size_t)(b - 2048) * 256 + tid) * 8; cvt8(wqa,  wqab,  i, f32); }
  else if (b < 3136)  { size_t i = ((size_t)(b - 2560) * 256 + tid) * 8; cvt8(wkva, wkvab, i, f32); }
  else {
    for (int i = tid; i < 512; i += 256) qabb[i]  = __float2bfloat16(rdv(qab,  i, f32));
    for (int i = tid; i < 576; i += 256) kvabb[i] = __float2bfloat16(rdv(kvab, i, f32));
  }
}

// convert wq_b (768 blks), wkv_b (1024), biases (2). Grid 1794.
__global__ __launch_bounds__(256) void convert_in2(
    const void* __restrict__ wqb, const void* __restrict__ wkvb,
    const void* __restrict__ qbb, const void* __restrict__ kvbb,
    bf16* __restrict__ wqbb, bf16* __restrict__ wkvbb,
    bf16* __restrict__ qbbb, bf16* __restrict__ kvbbb,
    const int* __restrict__ flagp)
{
  const int f32 = flagp[0];
  const int b = blockIdx.x, tid = threadIdx.x;
  if (b < 768)        { size_t i = ((size_t)b * 256 + tid) * 8;          cvt8(wqb,  wqbb,  i, f32); }
  else if (b < 1792)  { size_t i = ((size_t)(b - 768) * 256 + tid) * 8;  cvt8(wkvb, wkvbb, i, f32); }
  else if (b == 1792) { for (int i = tid; i < 3072; i += 256) qbbb[i]  = __float2bfloat16(rdv(qbb,  i, f32)); }
  else                { for (int i = tid; i < 4096; i += 256) kvbbb[i] = __float2bfloat16(rdv(kvbb, i, f32)); }
}

// convert wo (2048 blks) + wo bias (1 blk). Grid 2049. Only launched when
// ws_size provides the extra 10 MB region (host-side conditional).
__global__ __launch_bounds__(256) void convert_wo(
    const void* __restrict__ wo, const void* __restrict__ wob_in,
    bf16* __restrict__ wo16, bf16* __restrict__ wob16,
    const int* __restrict__ flagp)
{
  const int f32 = flagp[0];
  const int b = blockIdx.x, tid = threadIdx.x;
  if (b < 2048) { size_t i = ((size_t)b * 256 + tid) * 8; cvt8(wo, wo16, i, f32); }
  else { for (int i = tid; i < 2048; i += 256) wob16[i] = __float2bfloat16(rdv(wob_in, i, f32)); }
}

// ---------------- GEMM 128x128 body (round-7 logic + kbeg/kend/addbias) -----
template<int OMODE, bool A_DYN>
__device__ __forceinline__ void gemm128_body(
    const void* __restrict__ A, const void* __restrict__ W,
    const void* __restrict__ bias, void* __restrict__ Cout,
    int M, int N, int K, int f32in, int bx, int by,
    int kbeg, int kend, int addbias)
{
  __shared__ int4 As4[128 * 4];
  __shared__ int4 Bs4[128 * 4];
  const int tid = threadIdx.x, lane = tid & 63, wave = tid >> 6;
  const int grp = lane >> 4, l16 = lane & 15;
  const int m0 = bx * 128, n0 = by * 128;
  const int wm = (wave & 1) * 64, wn = (wave >> 1) * 64;
  float4x acc[4][4] = {};
  for (int k0 = kbeg; k0 < kend; k0 += 32) {
    if (!f32in) {
#pragma unroll
      for (int j = 0; j < 2; j++) {
        int row = wave * 32 + j * 16 + (lane >> 2);
        int cs = (lane & 3) ^ ((row >> 1) & 3);
        gload16((const bf16*)A + (size_t)(m0 + row) * K + k0 + cs * 8,
                &As4[(wave * 32 + j * 16) * 4]);
        gload16((const bf16*)W + (size_t)(n0 + row) * K + k0 + cs * 8,
                &Bs4[(wave * 32 + j * 16) * 4]);
      }
    } else {
#pragma unroll
      for (int i = 0; i < 2; i++) {
        int ch = tid + i * 256;
        int row = ch >> 2, c = ch & 3;
        int cs = c ^ ((row >> 1) & 3);
        size_t aoff = (size_t)(m0 + row) * K + k0 + cs * 8;
        size_t boff = (size_t)(n0 + row) * K + k0 + cs * 8;
        As4[row * 4 + c] = A_DYN ? pack8((const float*)A + aoff)
                                 : *(const int4*)((const bf16*)A + aoff);
        Bs4[row * 4 + c] = pack8((const float*)W + boff);
      }
    }
    __syncthreads();
    short8x af[4], bfr[4];
#pragma unroll
    for (int i = 0; i < 4; i++) {
      int ra = wm + i * 16 + l16;
      int rb = wn + i * 16 + l16;
      af[i]  = *(const short8x*)&As4[ra * 4 + (grp ^ ((ra >> 1) & 3))];
      bfr[i] = *(const short8x*)&Bs4[rb * 4 + (grp ^ ((rb >> 1) & 3))];
    }
#pragma unroll
    for (int i = 0; i < 4; i++)
#pragma unroll
      for (int j = 0; j < 4; j++)
        acc[i][j] = __builtin_amdgcn_mfma_f32_16x16x32_bf16(af[i], bfr[j], acc[i][j], 0, 0, 0);
    __syncthreads();
  }
#pragma unroll
  for (int j = 0; j < 4; j++) {
    int gn = n0 + wn + j * 16 + l16;
    float bv = addbias ? rdv(bias, gn, f32in) : 0.0f;
#pragma unroll
    for (int i = 0; i < 4; i++) {
      int gm0 = m0 + wm + i * 16 + grp * 4;
#pragma unroll
      for (int r = 0; r < 4; r++) {
        float v = acc[i][j][r] + bv;
        size_t idx = (size_t)(gm0 + r) * N + gn;
        if (OMODE == 0)      ((float*)Cout)[idx] = v;
        else if (OMODE == 1) ((bf16*)Cout)[idx] = __float2bfloat16(v);
        else {
          if (f32in) ((float*)Cout)[idx] = v;
          else       ((bf16*)Cout)[idx] = __float2bfloat16(v);
        }
      }
    }
  }
}

// q_b and kv_b in one dispatch (bf16 fast path: weights pre-converted):
// z=0 -> (qn,wq_b)->qbuf N=3072 (24 tiles); z=1 -> (kvn,wkv_b)->kvb N=4096.
__global__ __launch_bounds__(256) void gemmB_dual(
    const void* __restrict__ A0, const void* __restrict__ A1,
    const void* __restrict__ W0, const void* __restrict__ W1,
    const void* __restrict__ b0, const void* __restrict__ b1,
    void* __restrict__ C0, void* __restrict__ C1)
{
  const int z = blockIdx.z;
  if (z == 0 && blockIdx.y >= 24) return;
  const void* A = z ? A1 : A0;
  const void* W = z ? W1 : W0;
  const void* bias = z ? b1 : b0;
  void* C = z ? C1 : C0;
  const int N = z ? 4096 : 3072;
  gemm128_body<1, false>(A, W, bias, C, 2048, N, 512, 0,
                         blockIdx.x, blockIdx.y, 0, 512, 1);
}

// wo split-K=2, fp32-W fallback path (when ws lacks the bf16-wo region)
__global__ __launch_bounds__(256) void gemmWo_sk(
    const void* __restrict__ A, const void* __restrict__ W,
    const void* __restrict__ bias, float* __restrict__ part,
    const int* __restrict__ flagp)
{
  const int z = blockIdx.z;
  gemm128_body<0, false>(A, W, bias, part + (size_t)z * 2048 * 2048,
                         2048, 2048, 2048, flagp[0],
                         blockIdx.x, blockIdx.y, z * 1024, z * 1024 + 1024, z == 0);
}

// wo split-K=2, bf16 fast path (weights pre-converted by convert_wo)
__global__ __launch_bounds__(256) void gemmWo_sk_bf(
    const void* __restrict__ A, const void* __restrict__ W,
    const void* __restrict__ bias, float* __restrict__ part)
{
  const int z = blockIdx.z;
  gemm128_body<0, false>(A, W, bias, part + (size_t)z * 2048 * 2048,
                         2048, 2048, 2048, 0,
                         blockIdx.x, blockIdx.y, z * 1024, z * 1024 + 1024, z == 0);
}

// reduce: out = part0 + part1 (bias already in part0); out dtype per flag
__global__ __launch_bounds__(256) void reduce_out(
    const float* __restrict__ p0, const float* __restrict__ p1,
    void* __restrict__ out, const int* __restrict__ flagp)
{
  const int f32in = flagp[0];
  size_t i = ((size_t)blockIdx.x * 256 + threadIdx.x) * 4;
  float4 a = *(const float4*)(p0 + i);
  float4 b = *(const float4*)(p1 + i);
  a.x += b.x; a.y += b.y; a.z += b.z; a.w += b.w;
  if (f32in) {
    *(float4*)((float*)out + i) = a;
  } else {
    unsigned short h[4];
    bf16 t0 = __float2bfloat16(a.x); __builtin_memcpy(&h[0], &t0, 2);
    bf16 t1 = __float2bfloat16(a.y); __builtin_memcpy(&h[1], &t1, 2);
    bf16 t2 = __float2bfloat16(a.z); __builtin_memcpy(&h[2], &t2, 2);
    bf16 t3 = __float2bfloat16(a.w); __builtin_memcpy(&h[3], &t3, 2);
    int2 v;
    v.x = (int)((unsigned)h[0] | ((unsigned)h[1] << 16));
    v.y = (int)((unsigned)h[2] | ((unsigned)h[3] << 16));
    *(int2*)((bf16*)out + i) = v;
  }
}

// ---------------- GEMM 64x64 body (round-7 logic + kbeg/kend/addbias) -------
template<int OMODE, bool A_DYN>
__device__ __forceinline__ void gemm64_body(
    const void* __restrict__ A, const void* __restrict__ W,
    const void* __restrict__ bias, void* __restrict__ Cout,
    int M, int N, int K, int f32in, int bx, int by,
    int kbeg, int kend, int addbias)
{
  __shared__ int4 As4[64 * 4];
  __shared__ int4 Bs4[64 * 4];
  const int tid = threadIdx.x, lane = tid & 63, wave = tid >> 6;
  const int grp = lane >> 4, l16 = lane & 15;
  const int m0 = bx * 64, n0 = by * 64;
  const int wm = (wave & 1) * 32, wn = (wave >> 1) * 32;
  float4x acc[2][2] = {};
  for (int k0 = kbeg; k0 < kend; k0 += 32) {
    if (!f32in) {
      int row = wave * 16 + (lane >> 2);
      int cs = (lane & 3) ^ ((row >> 1) & 3);
      gload16((const bf16*)A + (size_t)(m0 + row) * K + k0 + cs * 8,
              &As4[wave * 16 * 4]);
      gload16((const bf16*)W + (size_t)(n0 + row) * K + k0 + cs * 8,
              &Bs4[wave * 16 * 4]);
    } else {
      int row = tid >> 2, c = tid & 3;
      int cs = c ^ ((row >> 1) & 3);
      size_t aoff = (size_t)(m0 + row) * K + k0 + cs * 8;
      size_t boff = (size_t)(n0 + row) * K + k0 + cs * 8;
      As4[row * 4 + c] = A_DYN ? pack8((const float*)A + aoff)
                               : *(const int4*)((const bf16*)A + aoff);
      Bs4[row * 4 + c] = pack8((const float*)W + boff);
    }
    __syncthreads();
    short8x af[2], bfr[2];
#pragma unroll
    for (int i = 0; i < 2; i++) {
      int ra = wm + i * 16 + l16;
      int rb = wn + i * 16 + l16;
      af[i]  = *(const short8x*)&As4[ra * 4 + (grp ^ ((ra >> 1) & 3))];
      bfr[i] = *(const short8x*)&Bs4[rb * 4 + (grp ^ ((rb >> 1) & 3))];
    }
#pragma unroll
    for (int i = 0; i < 2; i++)
#pragma unroll
      for (int j = 0; j < 2; j++)
        acc[i][j] = __builtin_amdgcn_mfma_f32_16x16x32_bf16(af[i], bfr[j], acc[i][j], 0, 0, 0);
    __syncthreads();
  }
#pragma unroll
  for (int j = 0; j < 2; j++) {
    int gn = n0 + wn + j * 16 + l16;
    float bv = addbias ? rdv(bias, gn, f32in) : 0.0f;
#pragma unroll
    for (int i = 0; i < 2; i++) {
      int gm0 = m0 + wm + i * 16 + grp * 4;
#pragma unroll
      for (int r = 0; r < 4; r++) {
        float v = acc[i][j][r] + bv;
        size_t idx = (size_t)(gm0 + r) * N + gn;
        if (OMODE == 0)      ((float*)Cout)[idx] = v;
        else if (OMODE == 1) ((bf16*)Cout)[idx] = __float2bfloat16(v);
        else {
          if (f32in) ((float*)Cout)[idx] = v;
          else       ((bf16*)Cout)[idx] = __float2bfloat16(v);
        }
      }
    }
  }
}

// q_a/kv_a projections on pre-converted bf16 inputs (fast gload16 path),
// split-K=2, fused: grid (32,9,4); z = (mat<<1)|khalf.
__global__ __launch_bounds__(256) void gemmA_sk(
    const void* __restrict__ A,
    const void* __restrict__ W0, const void* __restrict__ W1,
    const void* __restrict__ b0, const void* __restrict__ b1,
    float* __restrict__ C0, float* __restrict__ C1)
{
  const int z = blockIdx.z;
  const int mat = z >> 1, kh = z & 1;
  const int N = mat ? 576 : 512;
  if (blockIdx.y * 64 >= N) return;
  const void* W = mat ? W1 : W0;
  const void* bias = mat ? b1 : b0;
  float* C = (mat ? C1 : C0) + (size_t)kh * 2048 * N;
  gemm64_body<0, false>(A, W, bias, C, 2048, N, 2048, 0,
                        blockIdx.x, blockIdx.y,
                        kh * 1024, kh * 1024 + 1024, kh == 0);
}

// ------ merged norms w/ fused split-K reduce: b<2048 -> q; else kv ----------
__global__ __launch_bounds__(256) void norms_merged(
    const float* __restrict__ q_a0, const float* __restrict__ q_a1,
    const float* __restrict__ kv_a0, const float* __restrict__ kv_a1,
    const void* __restrict__ qw, const void* __restrict__ kvw,
    const void* __restrict__ cosb, const void* __restrict__ sinb,
    bf16* __restrict__ qn, bf16* __restrict__ kvn, bf16* __restrict__ kpe,
    const int* __restrict__ flagp)
{
  const int f32in = flagp[0];
  const int b = blockIdx.x, tid = threadIdx.x;
  __shared__ float red[4];
  if (b < 2048) {
    const int s = b;
    size_t base = (size_t)s * 512;
    float v0 = q_a0[base + tid] + q_a1[base + tid];
    float v1 = q_a0[base + tid + 256] + q_a1[base + tid + 256];
    float ss = v0 * v0 + v1 * v1;
#pragma unroll
    for (int off = 1; off < 64; off <<= 1) ss += __shfl_xor(ss, off);
    if ((tid & 63) == 0) red[tid >> 6] = ss;
    __syncthreads();
    float tot = red[0] + red[1] + red[2] + red[3];
    float scale = rsqrtf(tot * (1.0f / 512.0f) + EPS_F);
    qn[base + tid]       = __float2bfloat16(v0 * scale * rdv(qw, tid, f32in));
    qn[base + tid + 256] = __float2bfloat16(v1 * scale * rdv(qw, tid + 256, f32in));
  } else {
    const int s = b - 2048;
    size_t base = (size_t)s * 576;
    float v0 = kv_a0[base + tid] + kv_a1[base + tid];
    float v1 = kv_a0[base + tid + 256] + kv_a1[base + tid + 256];
    float ss = v0 * v0 + v1 * v1;
#pragma unroll
    for (int off = 1; off < 64; off <<= 1) ss += __shfl_xor(ss, off);
    if ((tid & 63) == 0) red[tid >> 6] = ss;
    __syncthreads();
    float tot = red[0] + red[1] + red[2] + red[3];
    float scale = rsqrtf(tot * (1.0f / 512.0f) + EPS_F);
    kvn[(size_t)s * 512 + tid]       = __float2bfloat16(v0 * scale * rdv(kvw, tid, f32in));
    kvn[(size_t)s * 512 + tid + 256] = __float2bfloat16(v1 * scale * rdv(kvw, tid + 256, f32in));
    if (tid < 32) {
      float x0 = kv_a0[base + 512 + 2 * tid] + kv_a1[base + 512 + 2 * tid];
      float x1 = kv_a0[base + 512 + 2 * tid + 1] + kv_a1[base + 512 + 2 * tid + 1];
      float c  = rdv(cosb, (size_t)s * 32 + tid, f32in);
      float sn = rdv(sinb, (size_t)s * 32 + tid, f32in);
      kpe[s * 64 + 2 * tid]     = __float2bfloat16(x0 * c - x1 * sn);
      kpe[s * 64 + 2 * tid + 1] = __float2bfloat16(x0 * sn + x1 * c);
    }
  }
}

// ------ merged rope_q (b<2048) + build_vt (b>=2048, 512 blocks) -------------
__global__ __launch_bounds__(256) void rope_vt_merged(
    bf16* __restrict__ q, const void* __restrict__ cosb,
    const void* __restrict__ sinb, const bf16* __restrict__ kvb,
    bf16* __restrict__ Vt, const int* __restrict__ flagp)
{
  const int b = blockIdx.x, tid = threadIdx.x;
  __shared__ __align__(16) bf16 tile[64][136];
  if (b < 2048) {
    const int f32in = flagp[0];
    const int s = b;
#pragma unroll
    for (int it = 0; it < 2; it++) {
      int p = tid + it * 256;
      int hh = p >> 5, jj = p & 31;
      bf16* src = q + (size_t)s * 3072 + hh * 192 + 128 + 2 * jj;
      float x0 = __bfloat162float(src[0]);
      float x1 = __bfloat162float(src[1]);
      float c  = rdv(cosb, (size_t)s * 32 + jj, f32in);
      float sn = rdv(sinb, (size_t)s * 32 + jj, f32in);
      src[0] = __float2bfloat16(x0 * c - x1 * sn);
      src[1] = __float2bfloat16(x0 * sn + x1 * c);
    }
  } else {
    const int hb = b - 2048;                 // 0..511
    const int h = hb & 15;
    const int t0 = (hb >> 4) * 64;
#pragma unroll
    for (int i = 0; i < 4; i++) {
      int chunk = tid + i * 256;
      int row = chunk >> 4;
      int c8 = (chunk & 15) * 8;
      *(int4*)&tile[row][c8] =
          *(const int4*)(kvb + (size_t)(t0 + row) * 4096 + h * 256 + 128 + c8);
    }
    __syncthreads();
#pragma unroll
    for (int i = 0; i < 32; i++) {
      int idx = tid + i * 256;
      int d = idx >> 6;
      int t = idx & 63;
      Vt[((size_t)h * 128 + d) * 2048 + t0 + t] = tile[t][d];
    }
  }
}

// ---------------- flash attention: round-0 staging/barriers EXACTLY
// (verified 81.7 µs; r1-r4 staging rewrites all regressed and stay reverted).
// This round isolates T5 (setprio around MFMA clusters) + T13 (defer-max,
// THR=8) on the compute phase only — the combination never tested clean. ----
__global__ __launch_bounds__(256) void attn_kernel(
    const bf16* __restrict__ Q, const bf16* __restrict__ kvb,
    const bf16* __restrict__ kpe, const bf16* __restrict__ Vt,
    bf16* __restrict__ Out)
{
  __shared__ __align__(16) bf16 Ks[64 * 200];
  __shared__ __align__(16) bf16 Vs[128 * 72];
  __shared__ __align__(16) bf16 plds[4][16 * 68];
  const int b = blockIdx.x;
  const int h = b & 15;
  const int tt = (b >> 4) & 15;
  const int q0 = ((b >> 8) ? (31 - tt) : tt) * 64;
  const int tid = threadIdx.x;
  const int wave = tid >> 6;
  const int lane = tid & 63;
  const int grp = lane >> 4, l16 = lane & 15;
  const int qrt = q0 + wave * 16;
  const bf16* Qbase = Q + (size_t)(qrt + l16) * 3072 + h * 192;
  short8x qf[6];
#pragma unroll
  for (int c = 0; c < 6; c++)
    qf[c] = *(const short8x*)(Qbase + c * 32 + grp * 8);
  float m_run[4], l_run[4];
  float4x o_acc[8] = {};
#pragma unroll
  for (int r = 0; r < 4; r++) { m_run[r] = -__builtin_inff(); l_run[r] = 0.f; }
  bf16* pl = &plds[wave][0];
  for (int t0 = 0; t0 <= q0; t0 += 64) {
#pragma unroll
    for (int i = 0; i < 4; i++) {
      int ch = tid + i * 256;
      int row = ch >> 4, c = ch & 15;
      *(int4*)&Ks[row * 200 + c * 8] =
          *(const int4*)(kvb + (size_t)(t0 + row) * 4096 + h * 256 + c * 8);
    }
#pragma unroll
    for (int i = 0; i < 2; i++) {
      int ch = tid + i * 256;
      int row = ch >> 3, c = ch & 7;
      *(int4*)&Ks[row * 200 + 128 + c * 8] =
          *(const int4*)(kpe + (size_t)(t0 + row) * 64 + c * 8);
    }
#pragma unroll
    for (int i = 0; i < 4; i++) {
      int ch = tid + i * 256;
      int row = ch >> 3, c = ch & 7;
      *(int4*)&Vs[row * 72 + c * 8] =
          *(const int4*)(Vt + ((size_t)h * 128 + row) * 2048 + t0 + c * 8);
    }
    __syncthreads();
    float4x sacc[4] = {};
    __builtin_amdgcn_s_setprio(1);
#pragma unroll
    for (int n = 0; n < 4; n++) {
      const bf16* Kb = &Ks[(n * 16 + l16) * 200 + grp * 8];
#pragma unroll
      for (int c = 0; c < 6; c++) {
        short8x kf = *(const short8x*)(Kb + c * 32);
        sacc[n] = __builtin_amdgcn_mfma_f32_16x16x32_bf16(qf[c], kf, sacc[n], 0, 0, 0);
      }
    }
    __builtin_amdgcn_s_setprio(0);

    // softmax with defer-max (T13, THR=8): skip the O/l rescale while the
    // running max doesn't grow by >8 (P bounded by e^8; fp32 acc tolerates).
    float p0[4][4], mxv[4];
    int grow = 0;
#pragma unroll
    for (int r = 0; r < 4; r++) {
      const int s_row = qrt + grp * 4 + r;
      float mx = -__builtin_inff();
#pragma unroll
      for (int n = 0; n < 4; n++) {
        int t = t0 + n * 16 + l16;
        float v = sacc[n][r] * SCALE_F;
        v = (t > s_row) ? -1.0e9f : v;
        p0[r][n] = v;
        mx = fmaxf(mx, v);
      }
      mx = fmaxf(mx, __shfl_xor(mx, 1));
      mx = fmaxf(mx, __shfl_xor(mx, 2));
      mx = fmaxf(mx, __shfl_xor(mx, 4));
      mx = fmaxf(mx, __shfl_xor(mx, 8));
      mxv[r] = mx;
      grow |= (mx > m_run[r] + 8.0f) ? 1 : 0;
    }
    if (__any(grow)) {
      float alpha[4];
#pragma unroll
      for (int r = 0; r < 4; r++) {
        float mn = fmaxf(m_run[r], mxv[r]);
        alpha[r] = __expf(m_run[r] - mn);
        m_run[r] = mn;
        l_run[r] *= alpha[r];
      }
#pragma unroll
      for (int n = 0; n < 8; n++)
#pragma unroll
        for (int r = 0; r < 4; r++)
          o_acc[n][r] *= alpha[r];
    }
    float pv[4][4];
#pragma unroll
    for (int r = 0; r < 4; r++) {
      float sum = 0.f;
#pragma unroll
      for (int n = 0; n < 4; n++) {
        float e = __expf(p0[r][n] - m_run[r]);
        pv[n][r] = e;
        sum += e;
      }
      sum += __shfl_xor(sum, 1);
      sum += __shfl_xor(sum, 2);
      sum += __shfl_xor(sum, 4);
      sum += __shfl_xor(sum, 8);
      l_run[r] += sum;
    }
#pragma unroll
    for (int n = 0; n < 4; n++)
#pragma unroll
      for (int r = 0; r < 4; r++)
        pl[(grp * 4 + r) * 68 + n * 16 + l16] = __float2bfloat16(pv[n][r]);

    __builtin_amdgcn_s_setprio(1);
#pragma unroll
    for (int c = 0; c < 2; c++) {
      union { short4x h4[2]; short8x v8; } pk;
      const bf16* pp = pl + l16 * 68 + c * 32 + grp * 8;
      pk.h4[0] = *(const short4x*)(pp);
      pk.h4[1] = *(const short4x*)(pp + 4);
#pragma unroll
      for (int n = 0; n < 8; n++) {
        short8x vf = *(const short8x*)&Vs[(size_t)(n * 16 + l16) * 72 + c * 32 + grp * 8];
        o_acc[n] = __builtin_amdgcn_mfma_f32_16x16x32_bf16(pk.v8, vf, o_acc[n], 0, 0, 0);
      }
    }
    __builtin_amdgcn_s_setprio(0);
    __syncthreads();
  }
  float inv[4];
#pragma unroll
  for (int r = 0; r < 4; r++) inv[r] = 1.0f / l_run[r];
#pragma unroll
  for (int n = 0; n < 8; n++)
#pragma unroll
    for (int r = 0; r < 4; r++) {
      int s_row = qrt + grp * 4 + r;
      Out[(size_t)s_row * 2048 + h * 128 + n * 16 + l16] =
          __float2bfloat16(o_acc[n][r] * inv[r]);
    }
}

extern "C" void kernel_launch(void* const* d_in, const int* in_sizes, int n_in,
                              void* d_out, int out_size, void* d_ws, size_t ws_size,
                              hipStream_t stream) {
  const void* x        = d_in[0];
  const void* fcos     = d_in[2];
  const void* fsin     = d_in[3];
  const void* wq_a_w   = d_in[5];
  const void* wq_a_b   = d_in[6];
  const void* q_norm_w = d_in[7];
  const void* wq_b_w   = d_in[8];
  const void* wq_b_b   = d_in[9];
  const void* wkv_a_w  = d_in[10];
  const void* wkv_a_b  = d_in[11];
  const void* kv_norm_w= d_in[12];
  const void* wkv_b_w  = d_in[13];
  const void* wkv_b_b  = d_in[14];
  const void* wo_w     = d_in[15];
  const void* wo_b     = d_in[16];

  const size_t KB = 1024, MB = 1024 * 1024;
  if (ws_size < 46 * MB) {   // diagnostic: absmax ~1000 => ws too small
    sentinel_kernel<<<(out_size + 255) / 256, 256, 0, stream>>>((bf16*)d_out, out_size);
    return;
  }
  char* ws = (char*)d_ws;
  // Region plan, peak 44.5 MB (46 MB guard). Persistent: kpe[0,0.25M)
  //   flag@0.25M qbuf[0.5,12.5) kvb[12.5,28.5) Vt[28.5,36.5) attnout[36.5,44.5).
  // Transients (time-disjoint with their hosts):
  //   kv_a0/1 [0.5,9.5)   in qbuf    (dead before gemmB writes qbuf)
  //   q_a0/1  [36.5,44.5) in attnout (dead before convert_in2)
  //   xb/wqab/wkvab/biasA [12.5,25.1) in kvb (dead before gemmB writes kvb)
  //   wqbb/wkvbb/biasB [36.5,43.8) in attnout (dead before attn writes attnout)
  //   qn/kvn  [28.5,32.5) in Vt      (dead before rope_vt writes Vt)
  //   wpart   [0.5,32.5)  in qbuf+kvb+Vt (all dead after attn)
  // OPTIONAL (only if ws_size >= 56 MB): wo16 [46,54), wob16 @54.5 — lets
  //   gemmWo run the bf16 fast path. Identical RNE rounding as in-kernel
  //   pack8, so numerics are unchanged.
  bf16*  kpe    = (bf16*)(ws);
  int*   flag   = (int*)(ws + 256 * KB);
  bf16*  qbuf   = (bf16*)(ws + 512 * KB);
  bf16*  kvb    = (bf16*)(ws + 12 * MB + 512 * KB);
  bf16*  Vt     = (bf16*)(ws + 28 * MB + 512 * KB);
  bf16*  attnout= (bf16*)(ws + 36 * MB + 512 * KB);
  float* kv_a0  = (float*)(ws + 512 * KB);
  float* kv_a1  = (float*)(ws + 5 * MB);
  float* q_a0   = (float*)(ws + 36 * MB + 512 * KB);
  float* q_a1   = (float*)(ws + 40 * MB + 512 * KB);
  bf16*  qn     = (bf16*)(ws + 28 * MB + 512 * KB);
  bf16*  kvn    = (bf16*)(ws + 30 * MB + 512 * KB);
  float* wpart  = (float*)(ws + 512 * KB);
  // bf16 conversion targets
  bf16*  xb     = (bf16*)(ws + 12 * MB + 512 * KB);   // 8MB   [12.5,20.5)
  bf16*  wqab   = (bf16*)(ws + 20 * MB + 512 * KB);   // 2MB   [20.5,22.5)
  bf16*  wkvab  = (bf16*)(ws + 22 * MB + 512 * KB);   // 2.25M [22.5,24.75)
  bf16*  qabb   = (bf16*)(ws + 25 * MB);              // 1KB
  bf16*  kvabb  = (bf16*)(ws + 25 * MB + 64 * KB);    // 1.2KB
  bf16*  wqbb   = (bf16*)(ws + 36 * MB + 512 * KB);   // 3MB   [36.5,39.5)
  bf16*  wkvbb  = (bf16*)(ws + 39 * MB + 512 * KB);   // 4MB   [39.5,43.5)
  bf16*  qbbb   = (bf16*)(ws + 43 * MB + 512 * KB);   // 6KB
  bf16*  kvbbb  = (bf16*)(ws + 43 * MB + 768 * KB);   // 8KB
  // optional wo fast-path region (beyond the 46MB guard)
  const bool wofast = (ws_size >= 56 * MB);
  bf16*  wo16   = (bf16*)(ws + 46 * MB);              // 8MB   [46,54)
  bf16*  wob16  = (bf16*)(ws + 54 * MB + 512 * KB);   // 4KB

  dim3 blk(256);
  detect_dtype<<<1, blk, 0, stream>>>((const unsigned short*)x, flag);
  // amortized fp32->bf16: x + A-stage weights/biases (into kvb region)
  convert_in1<<<3137, blk, 0, stream>>>(
      x, wq_a_w, wkv_a_w, wq_a_b, wkv_a_b, xb, wqab, wkvab, qabb, kvabb, flag);
  if (wofast)
    convert_wo<<<2049, blk, 0, stream>>>(wo_w, wo_b, wo16, wob16, flag);
  // q_a and kv_a projections on bf16 fast path, split-K=2
  gemmA_sk<<<dim3(32, 9, 4), blk, 0, stream>>>(
      xb, wqab, wkvab, qabb, kvabb, q_a0, kv_a0);
  // both norms + split-K reduce fused (4096 blocks)
  norms_merged<<<4096, blk, 0, stream>>>(
      q_a0, q_a1, kv_a0, kv_a1, q_norm_w, kv_norm_w, fcos, fsin,
      qn, kvn, kpe, flag);
  // B-stage weights/biases -> bf16 (into attnout region; q_a now dead)
  convert_in2<<<1794, blk, 0, stream>>>(
      wq_b_w, wkv_b_w, wq_b_b, wkv_b_b, wqbb, wkvbb, qbbb, kvbbb, flag);
  // q_b and kv_b fused on bf16 fast path (896 active blocks)
  gemmB_dual<<<dim3(16, 32, 2), blk, 0, stream>>>(
      qn, kvn, wqbb, wkvbb, qbbb, kvbbb, qbuf, kvb);
  // rope on q (in place) + V transpose fused (2560 blocks)
  rope_vt_merged<<<2560, blk, 0, stream>>>(qbuf, fcos, fsin, kvb, Vt, flag);
  // attention (round-0 staging + T5/T13 compute)
  attn_kernel<<<dim3(512), blk, 0, stream>>>(qbuf, kvb, kpe, Vt, attnout);
  // output projection split-K=2 (512 blocks) + reduce
  if (wofast)
    gemmWo_sk_bf<<<dim3(16, 16, 2), blk, 0, stream>>>(attnout, wo16, wob16, wpart);
  else
    gemmWo_sk<<<dim3(16, 16, 2), blk, 0, stream>>>(attnout, wo_w, wo_b, wpart, flag);
  reduce_out<<<4096, blk, 0, stream>>>(wpart, wpart + (size_t)2048 * 2048, d_out, flag);
}

// Round 7
// 326.720 us; speedup vs baseline: 1.2329x; 1.0036x over previous
//
#include <hip/hip_runtime.h>
#include <hip/hip_bf16.h>

typedef __attribute__((ext_vector_type(8))) short short8x;  // 8 bf16 = 4 VGPR
typedef __attribute__((ext_vector_type(4))) short short4x;  // 8B
typedef __attribute__((ext_vector_type(4))) float float4x;  // MFMA C/D
typedef __hip_bfloat16 bf16;

#define EPS_F 1.1920929e-07f
#define SCALE_F 0.07216878364870323f   // 192^-0.5

// flag semantics: 0 = primary inputs are bf16, 1 = primary inputs are fp32
__device__ inline float rdv(const void* p, size_t i, int f32) {
  return f32 ? ((const float*)p)[i] : __bfloat162float(((const bf16*)p)[i]);
}

__device__ inline int4 pack8(const float* s) {   // 8 fp32 -> 8 bf16 (RNE)
  unsigned short h[8];
#pragma unroll
  for (int t = 0; t < 8; t++) {
    bf16 b = __float2bfloat16(s[t]);
    __builtin_memcpy(&h[t], &b, 2);
  }
  int4 r;
  r.x = (int)((unsigned)h[0] | ((unsigned)h[1] << 16));
  r.y = (int)((unsigned)h[2] | ((unsigned)h[3] << 16));
  r.z = (int)((unsigned)h[4] | ((unsigned)h[5] << 16));
  r.w = (int)((unsigned)h[6] | ((unsigned)h[7] << 16));
  return r;
}

// async global->LDS, 16B per lane; LDS dest = wave-uniform base + lane*16
typedef __attribute__((address_space(1))) const unsigned int gu32;
typedef __attribute__((address_space(3))) unsigned int lu32;
__device__ __forceinline__ void gload16(const void* g, void* l) {
  __builtin_amdgcn_global_load_lds((gu32*)g, (lu32*)l, 16, 0, 0);
}

// -------- dtype detector --------
__global__ __launch_bounds__(256) void detect_dtype(const unsigned short* __restrict__ x,
                                                    int* __restrict__ flag) {
  int tid = threadIdx.x;
  int cnt = 0;
#pragma unroll
  for (int i = 0; i < 4; i++) {
    unsigned short u = x[tid * 4 + i];
    int e = (u >> 7) & 0xFF;
    cnt += (e >= 118 && e <= 130) ? 1 : 0;
  }
#pragma unroll
  for (int off = 1; off < 64; off <<= 1) cnt += __shfl_xor(cnt, off);
  __shared__ int red[4];
  if ((tid & 63) == 0) red[tid >> 6] = cnt;
  __syncthreads();
  if (tid == 0) flag[0] = ((red[0] + red[1] + red[2] + red[3]) > 768) ? 0 : 1;
}

__global__ __launch_bounds__(256) void sentinel_kernel(bf16* out, int n) {
  int i = blockIdx.x * 256 + threadIdx.x;
  if (i < n) out[i] = __float2bfloat16(1000.0f);
}

// -------- bf16 conversion helpers (amortize the fp32 path ONCE) -------------
__device__ __forceinline__ void cvt8(const void* src, bf16* dst, size_t i, int f32) {
  if (f32) {
    float4 a = *(const float4*)((const float*)src + i);
    float4 b = *(const float4*)((const float*)src + i + 4);
    float s[8] = {a.x, a.y, a.z, a.w, b.x, b.y, b.z, b.w};
    *(int4*)(dst + i) = pack8(s);
  } else {
    *(int4*)(dst + i) = *(const int4*)((const bf16*)src + i);
  }
}

// convert x (2048 blks), wq_a (512), wkv_a (576), biases (1 blk). Grid 3137.
__global__ __launch_bounds__(256) void convert_in1(
    const void* __restrict__ x, const void* __restrict__ wqa,
    const void* __restrict__ wkva,
    const void* __restrict__ qab, const void* __restrict__ kvab,
    bf16* __restrict__ xb, bf16* __restrict__ wqab, bf16* __restrict__ wkvab,
    bf16* __restrict__ qabb, bf16* __restrict__ kvabb,
    const int* __restrict__ flagp)
{
  const int f32 = flagp[0];
  const int b = blockIdx.x, tid = threadIdx.x;
  if (b < 2048)       { size_t i = ((size_t)b * 256 + tid) * 8;          cvt8(x,    xb,    i, f32); }
  else if (b < 2560)  { size_t i = ((size_t)(b - 2048) * 256 + tid) * 8; cvt8(wqa,  wqab,  i, f32); }
  else if (b < 3136)  { size_t i = ((size_t)(b - 2560) * 256 + tid) * 8; cvt8(wkva, wkvab, i, f32); }
  else {
    for (int i = tid; i < 512; i += 256) qabb[i]  = __float2bfloat16(rdv(qab,  i, f32));
    for (int i = tid; i < 576; i += 256) kvabb[i] = __float2bfloat16(rdv(kvab, i, f32));
  }
}

// convert wq_b (768 blks), wkv_b (1024), biases (2). Grid 1794.
__global__ __launch_bounds__(256) void convert_in2(
    const void* __restrict__ wqb, const void* __restrict__ wkvb,
    const void* __restrict__ qbb, const void* __restrict__ kvbb,
    bf16* __restrict__ wqbb, bf16* __restrict__ wkvbb,
    bf16* __restrict__ qbbb, bf16* __restrict__ kvbbb,
    const int* __restrict__ flagp)
{
  const int f32 = flagp[0];
  const int b = blockIdx.x, tid = threadIdx.x;
  if (b < 768)        { size_t i = ((size_t)b * 256 + tid) * 8;          cvt8(wqb,  wqbb,  i, f32); }
  else if (b < 1792)  { size_t i = ((size_t)(b - 768) * 256 + tid) * 8;  cvt8(wkvb, wkvbb, i, f32); }
  else if (b == 1792) { for (int i = tid; i < 3072; i += 256) qbbb[i]  = __float2bfloat16(rdv(qbb,  i, f32)); }
  else                { for (int i = tid; i < 4096; i += 256) kvbbb[i] = __float2bfloat16(rdv(kvbb, i, f32)); }
}

// convert wo (2048 blks) + wo bias (1 blk). Grid 2049. Only launched when
// ws_size provides the extra 10 MB region (host-side conditional).
__global__ __launch_bounds__(256) void convert_wo(
    const void* __restrict__ wo, const void* __restrict__ wob_in,
    bf16* __restrict__ wo16, bf16* __restrict__ wob16,
    const int* __restrict__ flagp)
{
  const int f32 = flagp[0];
  const int b = blockIdx.x, tid = threadIdx.x;
  if (b < 2048) { size_t i = ((size_t)b * 256 + tid) * 8; cvt8(wo, wo16, i, f32); }
  else { for (int i = tid; i < 2048; i += 256) wob16[i] = __float2bfloat16(rdv(wob_in, i, f32)); }
}

// ---------------- GEMM 128x128 body (round-7 logic + kbeg/kend/addbias) -----
template<int OMODE, bool A_DYN>
__device__ __forceinline__ void gemm128_body(
    const void* __restrict__ A, const void* __restrict__ W,
    const void* __restrict__ bias, void* __restrict__ Cout,
    int M, int N, int K, int f32in, int bx, int by,
    int kbeg, int kend, int addbias)
{
  __shared__ int4 As4[128 * 4];
  __shared__ int4 Bs4[128 * 4];
  const int tid = threadIdx.x, lane = tid & 63, wave = tid >> 6;
  const int grp = lane >> 4, l16 = lane & 15;
  const int m0 = bx * 128, n0 = by * 128;
  const int wm = (wave & 1) * 64, wn = (wave >> 1) * 64;
  float4x acc[4][4] = {};
  for (int k0 = kbeg; k0 < kend; k0 += 32) {
    if (!f32in) {
#pragma unroll
      for (int j = 0; j < 2; j++) {
        int row = wave * 32 + j * 16 + (lane >> 2);
        int cs = (lane & 3) ^ ((row >> 1) & 3);
        gload16((const bf16*)A + (size_t)(m0 + row) * K + k0 + cs * 8,
                &As4[(wave * 32 + j * 16) * 4]);
        gload16((const bf16*)W + (size_t)(n0 + row) * K + k0 + cs * 8,
                &Bs4[(wave * 32 + j * 16) * 4]);
      }
    } else {
#pragma unroll
      for (int i = 0; i < 2; i++) {
        int ch = tid + i * 256;
        int row = ch >> 2, c = ch & 3;
        int cs = c ^ ((row >> 1) & 3);
        size_t aoff = (size_t)(m0 + row) * K + k0 + cs * 8;
        size_t boff = (size_t)(n0 + row) * K + k0 + cs * 8;
        As4[row * 4 + c] = A_DYN ? pack8((const float*)A + aoff)
                                 : *(const int4*)((const bf16*)A + aoff);
        Bs4[row * 4 + c] = pack8((const float*)W + boff);
      }
    }
    __syncthreads();
    short8x af[4], bfr[4];
#pragma unroll
    for (int i = 0; i < 4; i++) {
      int ra = wm + i * 16 + l16;
      int rb = wn + i * 16 + l16;
      af[i]  = *(const short8x*)&As4[ra * 4 + (grp ^ ((ra >> 1) & 3))];
      bfr[i] = *(const short8x*)&Bs4[rb * 4 + (grp ^ ((rb >> 1) & 3))];
    }
#pragma unroll
    for (int i = 0; i < 4; i++)
#pragma unroll
      for (int j = 0; j < 4; j++)
        acc[i][j] = __builtin_amdgcn_mfma_f32_16x16x32_bf16(af[i], bfr[j], acc[i][j], 0, 0, 0);
    __syncthreads();
  }
#pragma unroll
  for (int j = 0; j < 4; j++) {
    int gn = n0 + wn + j * 16 + l16;
    float bv = addbias ? rdv(bias, gn, f32in) : 0.0f;
#pragma unroll
    for (int i = 0; i < 4; i++) {
      int gm0 = m0 + wm + i * 16 + grp * 4;
#pragma unroll
      for (int r = 0; r < 4; r++) {
        float v = acc[i][j][r] + bv;
        size_t idx = (size_t)(gm0 + r) * N + gn;
        if (OMODE == 0)      ((float*)Cout)[idx] = v;
        else if (OMODE == 1) ((bf16*)Cout)[idx] = __float2bfloat16(v);
        else {
          if (f32in) ((float*)Cout)[idx] = v;
          else       ((bf16*)Cout)[idx] = __float2bfloat16(v);
        }
      }
    }
  }
}

// q_b and kv_b in one dispatch (bf16 fast path: weights pre-converted):
// z=0 -> (qn,wq_b)->qbuf N=3072 (24 tiles); z=1 -> (kvn,wkv_b)->kvb N=4096.
__global__ __launch_bounds__(256) void gemmB_dual(
    const void* __restrict__ A0, const void* __restrict__ A1,
    const void* __restrict__ W0, const void* __restrict__ W1,
    const void* __restrict__ b0, const void* __restrict__ b1,
    void* __restrict__ C0, void* __restrict__ C1)
{
  const int z = blockIdx.z;
  if (z == 0 && blockIdx.y >= 24) return;
  const void* A = z ? A1 : A0;
  const void* W = z ? W1 : W0;
  const void* bias = z ? b1 : b0;
  void* C = z ? C1 : C0;
  const int N = z ? 4096 : 3072;
  gemm128_body<1, false>(A, W, bias, C, 2048, N, 512, 0,
                         blockIdx.x, blockIdx.y, 0, 512, 1);
}

// wo split-K=2, fp32-W fallback path (when ws lacks the bf16-wo region)
__global__ __launch_bounds__(256) void gemmWo_sk(
    const void* __restrict__ A, const void* __restrict__ W,
    const void* __restrict__ bias, float* __restrict__ part,
    const int* __restrict__ flagp)
{
  const int z = blockIdx.z;
  gemm128_body<0, false>(A, W, bias, part + (size_t)z * 2048 * 2048,
                         2048, 2048, 2048, flagp[0],
                         blockIdx.x, blockIdx.y, z * 1024, z * 1024 + 1024, z == 0);
}

// wo split-K=2, bf16 fast path (weights pre-converted by convert_wo)
__global__ __launch_bounds__(256) void gemmWo_sk_bf(
    const void* __restrict__ A, const void* __restrict__ W,
    const void* __restrict__ bias, float* __restrict__ part)
{
  const int z = blockIdx.z;
  gemm128_body<0, false>(A, W, bias, part + (size_t)z * 2048 * 2048,
                         2048, 2048, 2048, 0,
                         blockIdx.x, blockIdx.y, z * 1024, z * 1024 + 1024, z == 0);
}

// reduce: out = part0 + part1 (bias already in part0); out dtype per flag
__global__ __launch_bounds__(256) void reduce_out(
    const float* __restrict__ p0, const float* __restrict__ p1,
    void* __restrict__ out, const int* __restrict__ flagp)
{
  const int f32in = flagp[0];
  size_t i = ((size_t)blockIdx.x * 256 + threadIdx.x) * 4;
  float4 a = *(const float4*)(p0 + i);
  float4 b = *(const float4*)(p1 + i);
  a.x += b.x; a.y += b.y; a.z += b.z; a.w += b.w;
  if (f32in) {
    *(float4*)((float*)out + i) = a;
  } else {
    unsigned short h[4];
    bf16 t0 = __float2bfloat16(a.x); __builtin_memcpy(&h[0], &t0, 2);
    bf16 t1 = __float2bfloat16(a.y); __builtin_memcpy(&h[1], &t1, 2);
    bf16 t2 = __float2bfloat16(a.z); __builtin_memcpy(&h[2], &t2, 2);
    bf16 t3 = __float2bfloat16(a.w); __builtin_memcpy(&h[3], &t3, 2);
    int2 v;
    v.x = (int)((unsigned)h[0] | ((unsigned)h[1] << 16));
    v.y = (int)((unsigned)h[2] | ((unsigned)h[3] << 16));
    *(int2*)((bf16*)out + i) = v;
  }
}

// ---------------- GEMM 64x64 body (round-7 logic + kbeg/kend/addbias) -------
template<int OMODE, bool A_DYN>
__device__ __forceinline__ void gemm64_body(
    const void* __restrict__ A, const void* __restrict__ W,
    const void* __restrict__ bias, void* __restrict__ Cout,
    int M, int N, int K, int f32in, int bx, int by,
    int kbeg, int kend, int addbias)
{
  __shared__ int4 As4[64 * 4];
  __shared__ int4 Bs4[64 * 4];
  const int tid = threadIdx.x, lane = tid & 63, wave = tid >> 6;
  const int grp = lane >> 4, l16 = lane & 15;
  const int m0 = bx * 64, n0 = by * 64;
  const int wm = (wave & 1) * 32, wn = (wave >> 1) * 32;
  float4x acc[2][2] = {};
  for (int k0 = kbeg; k0 < kend; k0 += 32) {
    if (!f32in) {
      int row = wave * 16 + (lane >> 2);
      int cs = (lane & 3) ^ ((row >> 1) & 3);
      gload16((const bf16*)A + (size_t)(m0 + row) * K + k0 + cs * 8,
              &As4[wave * 16 * 4]);
      gload16((const bf16*)W + (size_t)(n0 + row) * K + k0 + cs * 8,
              &Bs4[wave * 16 * 4]);
    } else {
      int row = tid >> 2, c = tid & 3;
      int cs = c ^ ((row >> 1) & 3);
      size_t aoff = (size_t)(m0 + row) * K + k0 + cs * 8;
      size_t boff = (size_t)(n0 + row) * K + k0 + cs * 8;
      As4[row * 4 + c] = A_DYN ? pack8((const float*)A + aoff)
                               : *(const int4*)((const bf16*)A + aoff);
      Bs4[row * 4 + c] = pack8((const float*)W + boff);
    }
    __syncthreads();
    short8x af[2], bfr[2];
#pragma unroll
    for (int i = 0; i < 2; i++) {
      int ra = wm + i * 16 + l16;
      int rb = wn + i * 16 + l16;
      af[i]  = *(const short8x*)&As4[ra * 4 + (grp ^ ((ra >> 1) & 3))];
      bfr[i] = *(const short8x*)&Bs4[rb * 4 + (grp ^ ((rb >> 1) & 3))];
    }
#pragma unroll
    for (int i = 0; i < 2; i++)
#pragma unroll
      for (int j = 0; j < 2; j++)
        acc[i][j] = __builtin_amdgcn_mfma_f32_16x16x32_bf16(af[i], bfr[j], acc[i][j], 0, 0, 0);
    __syncthreads();
  }
#pragma unroll
  for (int j = 0; j < 2; j++) {
    int gn = n0 + wn + j * 16 + l16;
    float bv = addbias ? rdv(bias, gn, f32in) : 0.0f;
#pragma unroll
    for (int i = 0; i < 2; i++) {
      int gm0 = m0 + wm + i * 16 + grp * 4;
#pragma unroll
      for (int r = 0; r < 4; r++) {
        float v = acc[i][j][r] + bv;
        size_t idx = (size_t)(gm0 + r) * N + gn;
        if (OMODE == 0)      ((float*)Cout)[idx] = v;
        else if (OMODE == 1) ((bf16*)Cout)[idx] = __float2bfloat16(v);
        else {
          if (f32in) ((float*)Cout)[idx] = v;
          else       ((bf16*)Cout)[idx] = __float2bfloat16(v);
        }
      }
    }
  }
}

// q_a/kv_a projections on pre-converted bf16 inputs (fast gload16 path),
// split-K=2, fused: grid (32,9,4); z = (mat<<1)|khalf.
__global__ __launch_bounds__(256) void gemmA_sk(
    const void* __restrict__ A,
    const void* __restrict__ W0, const void* __restrict__ W1,
    const void* __restrict__ b0, const void* __restrict__ b1,
    float* __restrict__ C0, float* __restrict__ C1)
{
  const int z = blockIdx.z;
  const int mat = z >> 1, kh = z & 1;
  const int N = mat ? 576 : 512;
  if (blockIdx.y * 64 >= N) return;
  const void* W = mat ? W1 : W0;
  const void* bias = mat ? b1 : b0;
  float* C = (mat ? C1 : C0) + (size_t)kh * 2048 * N;
  gemm64_body<0, false>(A, W, bias, C, 2048, N, 2048, 0,
                        blockIdx.x, blockIdx.y,
                        kh * 1024, kh * 1024 + 1024, kh == 0);
}

// ------ merged norms w/ fused split-K reduce: b<2048 -> q; else kv ----------
__global__ __launch_bounds__(256) void norms_merged(
    const float* __restrict__ q_a0, const float* __restrict__ q_a1,
    const float* __restrict__ kv_a0, const float* __restrict__ kv_a1,
    const void* __restrict__ qw, const void* __restrict__ kvw,
    const void* __restrict__ cosb, const void* __restrict__ sinb,
    bf16* __restrict__ qn, bf16* __restrict__ kvn, bf16* __restrict__ kpe,
    const int* __restrict__ flagp)
{
  const int f32in = flagp[0];
  const int b = blockIdx.x, tid = threadIdx.x;
  __shared__ float red[4];
  if (b < 2048) {
    const int s = b;
    size_t base = (size_t)s * 512;
    float v0 = q_a0[base + tid] + q_a1[base + tid];
    float v1 = q_a0[base + tid + 256] + q_a1[base + tid + 256];
    float ss = v0 * v0 + v1 * v1;
#pragma unroll
    for (int off = 1; off < 64; off <<= 1) ss += __shfl_xor(ss, off);
    if ((tid & 63) == 0) red[tid >> 6] = ss;
    __syncthreads();
    float tot = red[0] + red[1] + red[2] + red[3];
    float scale = rsqrtf(tot * (1.0f / 512.0f) + EPS_F);
    qn[base + tid]       = __float2bfloat16(v0 * scale * rdv(qw, tid, f32in));
    qn[base + tid + 256] = __float2bfloat16(v1 * scale * rdv(qw, tid + 256, f32in));
  } else {
    const int s = b - 2048;
    size_t base = (size_t)s * 576;
    float v0 = kv_a0[base + tid] + kv_a1[base + tid];
    float v1 = kv_a0[base + tid + 256] + kv_a1[base + tid + 256];
    float ss = v0 * v0 + v1 * v1;
#pragma unroll
    for (int off = 1; off < 64; off <<= 1) ss += __shfl_xor(ss, off);
    if ((tid & 63) == 0) red[tid >> 6] = ss;
    __syncthreads();
    float tot = red[0] + red[1] + red[2] + red[3];
    float scale = rsqrtf(tot * (1.0f / 512.0f) + EPS_F);
    kvn[(size_t)s * 512 + tid]       = __float2bfloat16(v0 * scale * rdv(kvw, tid, f32in));
    kvn[(size_t)s * 512 + tid + 256] = __float2bfloat16(v1 * scale * rdv(kvw, tid + 256, f32in));
    if (tid < 32) {
      float x0 = kv_a0[base + 512 + 2 * tid] + kv_a1[base + 512 + 2 * tid];
      float x1 = kv_a0[base + 512 + 2 * tid + 1] + kv_a1[base + 512 + 2 * tid + 1];
      float c  = rdv(cosb, (size_t)s * 32 + tid, f32in);
      float sn = rdv(sinb, (size_t)s * 32 + tid, f32in);
      kpe[s * 64 + 2 * tid]     = __float2bfloat16(x0 * c - x1 * sn);
      kpe[s * 64 + 2 * tid + 1] = __float2bfloat16(x0 * sn + x1 * c);
    }
  }
}

// ------ merged rope_q (b<2048) + build_vt (b>=2048, 512 blocks) -------------
__global__ __launch_bounds__(256) void rope_vt_merged(
    bf16* __restrict__ q, const void* __restrict__ cosb,
    const void* __restrict__ sinb, const bf16* __restrict__ kvb,
    bf16* __restrict__ Vt, const int* __restrict__ flagp)
{
  const int b = blockIdx.x, tid = threadIdx.x;
  __shared__ __align__(16) bf16 tile[64][136];
  if (b < 2048) {
    const int f32in = flagp[0];
    const int s = b;
#pragma unroll
    for (int it = 0; it < 2; it++) {
      int p = tid + it * 256;
      int hh = p >> 5, jj = p & 31;
      bf16* src = q + (size_t)s * 3072 + hh * 192 + 128 + 2 * jj;
      float x0 = __bfloat162float(src[0]);
      float x1 = __bfloat162float(src[1]);
      float c  = rdv(cosb, (size_t)s * 32 + jj, f32in);
      float sn = rdv(sinb, (size_t)s * 32 + jj, f32in);
      src[0] = __float2bfloat16(x0 * c - x1 * sn);
      src[1] = __float2bfloat16(x0 * sn + x1 * c);
    }
  } else {
    const int hb = b - 2048;                 // 0..511
    const int h = hb & 15;
    const int t0 = (hb >> 4) * 64;
#pragma unroll
    for (int i = 0; i < 4; i++) {
      int chunk = tid + i * 256;
      int row = chunk >> 4;
      int c8 = (chunk & 15) * 8;
      *(int4*)&tile[row][c8] =
          *(const int4*)(kvb + (size_t)(t0 + row) * 4096 + h * 256 + 128 + c8);
    }
    __syncthreads();
#pragma unroll
    for (int i = 0; i < 32; i++) {
      int idx = tid + i * 256;
      int d = idx >> 6;
      int t = idx & 63;
      Vt[((size_t)h * 128 + d) * 2048 + t0 + t] = tile[t][d];
    }
  }
}

// ---------------- flash attention (round-0 exact — verified 81.5-81.7 µs in
// r0/r5 and the original session; r1-r4 staging rewrites and r6's T5/T13
// compute-phase changes ALL regressed and are reverted. attn is closed). -----
__global__ __launch_bounds__(256) void attn_kernel(
    const bf16* __restrict__ Q, const bf16* __restrict__ kvb,
    const bf16* __restrict__ kpe, const bf16* __restrict__ Vt,
    bf16* __restrict__ Out)
{
  __shared__ __align__(16) bf16 Ks[64 * 200];
  __shared__ __align__(16) bf16 Vs[128 * 72];
  __shared__ __align__(16) bf16 plds[4][16 * 68];
  const int b = blockIdx.x;
  const int h = b & 15;
  const int tt = (b >> 4) & 15;
  const int q0 = ((b >> 8) ? (31 - tt) : tt) * 64;
  const int tid = threadIdx.x;
  const int wave = tid >> 6;
  const int lane = tid & 63;
  const int grp = lane >> 4, l16 = lane & 15;
  const int qrt = q0 + wave * 16;
  const bf16* Qbase = Q + (size_t)(qrt + l16) * 3072 + h * 192;
  short8x qf[6];
#pragma unroll
  for (int c = 0; c < 6; c++)
    qf[c] = *(const short8x*)(Qbase + c * 32 + grp * 8);
  float m_run[4], l_run[4];
  float4x o_acc[8] = {};
#pragma unroll
  for (int r = 0; r < 4; r++) { m_run[r] = -__builtin_inff(); l_run[r] = 0.f; }
  bf16* pl = &plds[wave][0];
  for (int t0 = 0; t0 <= q0; t0 += 64) {
#pragma unroll
    for (int i = 0; i < 4; i++) {
      int ch = tid + i * 256;
      int row = ch >> 4, c = ch & 15;
      *(int4*)&Ks[row * 200 + c * 8] =
          *(const int4*)(kvb + (size_t)(t0 + row) * 4096 + h * 256 + c * 8);
    }
#pragma unroll
    for (int i = 0; i < 2; i++) {
      int ch = tid + i * 256;
      int row = ch >> 3, c = ch & 7;
      *(int4*)&Ks[row * 200 + 128 + c * 8] =
          *(const int4*)(kpe + (size_t)(t0 + row) * 64 + c * 8);
    }
#pragma unroll
    for (int i = 0; i < 4; i++) {
      int ch = tid + i * 256;
      int row = ch >> 3, c = ch & 7;
      *(int4*)&Vs[row * 72 + c * 8] =
          *(const int4*)(Vt + ((size_t)h * 128 + row) * 2048 + t0 + c * 8);
    }
    __syncthreads();
    float4x sacc[4] = {};
#pragma unroll
    for (int n = 0; n < 4; n++) {
      const bf16* Kb = &Ks[(n * 16 + l16) * 200 + grp * 8];
#pragma unroll
      for (int c = 0; c < 6; c++) {
        short8x kf = *(const short8x*)(Kb + c * 32);
        sacc[n] = __builtin_amdgcn_mfma_f32_16x16x32_bf16(qf[c], kf, sacc[n], 0, 0, 0);
      }
    }
    float pv[4][4], alpha[4];
#pragma unroll
    for (int r = 0; r < 4; r++) {
      const int s_row = qrt + grp * 4 + r;
      float p0[4];
      float mx = -__builtin_inff();
#pragma unroll
      for (int n = 0; n < 4; n++) {
        int t = t0 + n * 16 + l16;
        float v = sacc[n][r] * SCALE_F;
        v = (t > s_row) ? -1.0e9f : v;
        p0[n] = v;
        mx = fmaxf(mx, v);
      }
      mx = fmaxf(mx, __shfl_xor(mx, 1));
      mx = fmaxf(mx, __shfl_xor(mx, 2));
      mx = fmaxf(mx, __shfl_xor(mx, 4));
      mx = fmaxf(mx, __shfl_xor(mx, 8));
      float m_new = fmaxf(m_run[r], mx);
      float a = __expf(m_run[r] - m_new);
      m_run[r] = m_new;
      float sum = 0.f;
#pragma unroll
      for (int n = 0; n < 4; n++) {
        float e = __expf(p0[n] - m_new);
        pv[n][r] = e;
        sum += e;
      }
      sum += __shfl_xor(sum, 1);
      sum += __shfl_xor(sum, 2);
      sum += __shfl_xor(sum, 4);
      sum += __shfl_xor(sum, 8);
      l_run[r] = l_run[r] * a + sum;
      alpha[r] = a;
    }
#pragma unroll
    for (int n = 0; n < 8; n++)
#pragma unroll
      for (int r = 0; r < 4; r++)
        o_acc[n][r] *= alpha[r];
#pragma unroll
    for (int n = 0; n < 4; n++)
#pragma unroll
      for (int r = 0; r < 4; r++)
        pl[(grp * 4 + r) * 68 + n * 16 + l16] = __float2bfloat16(pv[n][r]);
#pragma unroll
    for (int c = 0; c < 2; c++) {
      union { short4x h4[2]; short8x v8; } pk;
      const bf16* pp = pl + l16 * 68 + c * 32 + grp * 8;
      pk.h4[0] = *(const short4x*)(pp);
      pk.h4[1] = *(const short4x*)(pp + 4);
#pragma unroll
      for (int n = 0; n < 8; n++) {
        short8x vf = *(const short8x*)&Vs[(size_t)(n * 16 + l16) * 72 + c * 32 + grp * 8];
        o_acc[n] = __builtin_amdgcn_mfma_f32_16x16x32_bf16(pk.v8, vf, o_acc[n], 0, 0, 0);
      }
    }
    __syncthreads();
  }
  float inv[4];
#pragma unroll
  for (int r = 0; r < 4; r++) inv[r] = 1.0f / l_run[r];
#pragma unroll
  for (int n = 0; n < 8; n++)
#pragma unroll
    for (int r = 0; r < 4; r++) {
      int s_row = qrt + grp * 4 + r;
      Out[(size_t)s_row * 2048 + h * 128 + n * 16 + l16] =
          __float2bfloat16(o_acc[n][r] * inv[r]);
    }
}

extern "C" void kernel_launch(void* const* d_in, const int* in_sizes, int n_in,
                              void* d_out, int out_size, void* d_ws, size_t ws_size,
                              hipStream_t stream) {
  const void* x        = d_in[0];
  const void* fcos     = d_in[2];
  const void* fsin     = d_in[3];
  const void* wq_a_w   = d_in[5];
  const void* wq_a_b   = d_in[6];
  const void* q_norm_w = d_in[7];
  const void* wq_b_w   = d_in[8];
  const void* wq_b_b   = d_in[9];
  const void* wkv_a_w  = d_in[10];
  const void* wkv_a_b  = d_in[11];
  const void* kv_norm_w= d_in[12];
  const void* wkv_b_w  = d_in[13];
  const void* wkv_b_b  = d_in[14];
  const void* wo_w     = d_in[15];
  const void* wo_b     = d_in[16];

  const size_t KB = 1024, MB = 1024 * 1024;
  if (ws_size < 46 * MB) {   // diagnostic: absmax ~1000 => ws too small
    sentinel_kernel<<<(out_size + 255) / 256, 256, 0, stream>>>((bf16*)d_out, out_size);
    return;
  }
  char* ws = (char*)d_ws;
  // Region plan, peak 44.5 MB (46 MB guard). Persistent: kpe[0,0.25M)
  //   flag@0.25M qbuf[0.5,12.5) kvb[12.5,28.5) Vt[28.5,36.5) attnout[36.5,44.5).
  // Transients (time-disjoint with their hosts):
  //   kv_a0/1 [0.5,9.5)   in qbuf    (dead before gemmB writes qbuf)
  //   q_a0/1  [36.5,44.5) in attnout (dead before convert_in2)
  //   xb/wqab/wkvab/biasA [12.5,25.1) in kvb (dead before gemmB writes kvb)
  //   wqbb/wkvbb/biasB [36.5,43.8) in attnout (dead before attn writes attnout)
  //   qn/kvn  [28.5,32.5) in Vt      (dead before rope_vt writes Vt)
  //   wpart   [0.5,32.5)  in qbuf+kvb+Vt (all dead after attn)
  // OPTIONAL (only if ws_size >= 56 MB): wo16 [46,54), wob16 @54.5 — lets
  //   gemmWo run the bf16 fast path. Identical RNE rounding as in-kernel
  //   pack8, so numerics are unchanged. (Verified win in round 6.)
  bf16*  kpe    = (bf16*)(ws);
  int*   flag   = (int*)(ws + 256 * KB);
  bf16*  qbuf   = (bf16*)(ws + 512 * KB);
  bf16*  kvb    = (bf16*)(ws + 12 * MB + 512 * KB);
  bf16*  Vt     = (bf16*)(ws + 28 * MB + 512 * KB);
  bf16*  attnout= (bf16*)(ws + 36 * MB + 512 * KB);
  float* kv_a0  = (float*)(ws + 512 * KB);
  float* kv_a1  = (float*)(ws + 5 * MB);
  float* q_a0   = (float*)(ws + 36 * MB + 512 * KB);
  float* q_a1   = (float*)(ws + 40 * MB + 512 * KB);
  bf16*  qn     = (bf16*)(ws + 28 * MB + 512 * KB);
  bf16*  kvn    = (bf16*)(ws + 30 * MB + 512 * KB);
  float* wpart  = (float*)(ws + 512 * KB);
  // bf16 conversion targets
  bf16*  xb     = (bf16*)(ws + 12 * MB + 512 * KB);   // 8MB   [12.5,20.5)
  bf16*  wqab   = (bf16*)(ws + 20 * MB + 512 * KB);   // 2MB   [20.5,22.5)
  bf16*  wkvab  = (bf16*)(ws + 22 * MB + 512 * KB);   // 2.25M [22.5,24.75)
  bf16*  qabb   = (bf16*)(ws + 25 * MB);              // 1KB
  bf16*  kvabb  = (bf16*)(ws + 25 * MB + 64 * KB);    // 1.2KB
  bf16*  wqbb   = (bf16*)(ws + 36 * MB + 512 * KB);   // 3MB   [36.5,39.5)
  bf16*  wkvbb  = (bf16*)(ws + 39 * MB + 512 * KB);   // 4MB   [39.5,43.5)
  bf16*  qbbb   = (bf16*)(ws + 43 * MB + 512 * KB);   // 6KB
  bf16*  kvbbb  = (bf16*)(ws + 43 * MB + 768 * KB);   // 8KB
  // optional wo fast-path region (beyond the 46MB guard)
  const bool wofast = (ws_size >= 56 * MB);
  bf16*  wo16   = (bf16*)(ws + 46 * MB);              // 8MB   [46,54)
  bf16*  wob16  = (bf16*)(ws + 54 * MB + 512 * KB);   // 4KB

  dim3 blk(256);
  detect_dtype<<<1, blk, 0, stream>>>((const unsigned short*)x, flag);
  // amortized fp32->bf16: x + A-stage weights/biases (into kvb region)
  convert_in1<<<3137, blk, 0, stream>>>(
      x, wq_a_w, wkv_a_w, wq_a_b, wkv_a_b, xb, wqab, wkvab, qabb, kvabb, flag);
  if (wofast)
    convert_wo<<<2049, blk, 0, stream>>>(wo_w, wo_b, wo16, wob16, flag);
  // q_a and kv_a projections on bf16 fast path, split-K=2
  gemmA_sk<<<dim3(32, 9, 4), blk, 0, stream>>>(
      xb, wqab, wkvab, qabb, kvabb, q_a0, kv_a0);
  // both norms + split-K reduce fused (4096 blocks)
  norms_merged<<<4096, blk, 0, stream>>>(
      q_a0, q_a1, kv_a0, kv_a1, q_norm_w, kv_norm_w, fcos, fsin,
      qn, kvn, kpe, flag);
  // B-stage weights/biases -> bf16 (into attnout region; q_a now dead)
  convert_in2<<<1794, blk, 0, stream>>>(
      wq_b_w, wkv_b_w, wq_b_b, wkv_b_b, wqbb, wkvbb, qbbb, kvbbb, flag);
  // q_b and kv_b fused on bf16 fast path (896 active blocks)
  gemmB_dual<<<dim3(16, 32, 2), blk, 0, stream>>>(
      qn, kvn, wqbb, wkvbb, qbbb, kvbbb, qbuf, kvb);
  // rope on q (in place) + V transpose fused (2560 blocks)
  rope_vt_merged<<<2560, blk, 0, stream>>>(qbuf, fcos, fsin, kvb, Vt, flag);
  // attention (round-0 exact)
  attn_kernel<<<dim3(512), blk, 0, stream>>>(qbuf, kvb, kpe, Vt, attnout);
  // output projection split-K=2 (512 blocks) + reduce
  if (wofast)
    gemmWo_sk_bf<<<dim3(16, 16, 2), blk, 0, stream>>>(attnout, wo16, wob16, wpart);
  else
    gemmWo_sk<<<dim3(16, 16, 2), blk, 0, stream>>>(attnout, wo_w, wo_b, wpart, flag);
  reduce_out<<<4096, blk, 0, stream>>>(wpart, wpart + (size_t)2048 * 2048, d_out, flag);
}

// Round 8
// 315.282 us; speedup vs baseline: 1.2776x; 1.0363x over previous
//
#include <hip/hip_runtime.h>
#include <hip/hip_bf16.h>

typedef __attribute__((ext_vector_type(8))) short short8x;  // 8 bf16 = 4 VGPR
typedef __attribute__((ext_vector_type(4))) short short4x;  // 8B
typedef __attribute__((ext_vector_type(4))) float float4x;  // MFMA C/D
typedef __hip_bfloat16 bf16;

#define EPS_F 1.1920929e-07f
#define SCALE_F 0.07216878364870323f   // 192^-0.5

// flag semantics: 0 = primary inputs are bf16, 1 = primary inputs are fp32
__device__ inline float rdv(const void* p, size_t i, int f32) {
  return f32 ? ((const float*)p)[i] : __bfloat162float(((const bf16*)p)[i]);
}

__device__ inline int4 pack8(const float* s) {   // 8 fp32 -> 8 bf16 (RNE)
  unsigned short h[8];
#pragma unroll
  for (int t = 0; t < 8; t++) {
    bf16 b = __float2bfloat16(s[t]);
    __builtin_memcpy(&h[t], &b, 2);
  }
  int4 r;
  r.x = (int)((unsigned)h[0] | ((unsigned)h[1] << 16));
  r.y = (int)((unsigned)h[2] | ((unsigned)h[3] << 16));
  r.z = (int)((unsigned)h[4] | ((unsigned)h[5] << 16));
  r.w = (int)((unsigned)h[6] | ((unsigned)h[7] << 16));
  return r;
}

// async global->LDS, 16B per lane; LDS dest = wave-uniform base + lane*16
typedef __attribute__((address_space(1))) const unsigned int gu32;
typedef __attribute__((address_space(3))) unsigned int lu32;
__device__ __forceinline__ void gload16(const void* g, void* l) {
  __builtin_amdgcn_global_load_lds((gu32*)g, (lu32*)l, 16, 0, 0);
}

// -------- dtype detection (criterion shared by detect_dtype & convert_all) --
__device__ __forceinline__ int detect_exponents(const unsigned short* __restrict__ x,
                                                int tid, int* red) {
  int cnt = 0;
#pragma unroll
  for (int i = 0; i < 4; i++) {
    unsigned short u = x[tid * 4 + i];
    int e = (u >> 7) & 0xFF;
    cnt += (e >= 118 && e <= 130) ? 1 : 0;
  }
#pragma unroll
  for (int off = 1; off < 64; off <<= 1) cnt += __shfl_xor(cnt, off);
  if ((tid & 63) == 0) red[tid >> 6] = cnt;
  __syncthreads();
  return ((red[0] + red[1] + red[2] + red[3]) > 768) ? 0 : 1;
}

__global__ __launch_bounds__(256) void detect_dtype(const unsigned short* __restrict__ x,
                                                    int* __restrict__ flag) {
  __shared__ int red[4];
  int f = detect_exponents(x, threadIdx.x, red);
  if (threadIdx.x == 0) flag[0] = f;
}

__global__ __launch_bounds__(256) void sentinel_kernel(bf16* out, int n) {
  int i = blockIdx.x * 256 + threadIdx.x;
  if (i < n) out[i] = __float2bfloat16(1000.0f);
}

// -------- bf16 conversion helpers (amortize the fp32 path ONCE) -------------
__device__ __forceinline__ void cvt8(const void* src, bf16* dst, size_t i, int f32) {
  if (f32) {
    float4 a = *(const float4*)((const float*)src + i);
    float4 b = *(const float4*)((const float*)src + i + 4);
    float s[8] = {a.x, a.y, a.z, a.w, b.x, b.y, b.z, b.w};
    *(int4*)(dst + i) = pack8(s);
  } else {
    *(int4*)(dst + i) = *(const int4*)((const bf16*)src + i);
  }
}

// convert x (2048 blks), wq_a (512), wkv_a (576), biases (1 blk). Grid 3137.
__global__ __launch_bounds__(256) void convert_in1(
    const void* __restrict__ x, const void* __restrict__ wqa,
    const void* __restrict__ wkva,
    const void* __restrict__ qab, const void* __restrict__ kvab,
    bf16* __restrict__ xb, bf16* __restrict__ wqab, bf16* __restrict__ wkvab,
    bf16* __restrict__ qabb, bf16* __restrict__ kvabb,
    const int* __restrict__ flagp)
{
  const int f32 = flagp[0];
  const int b = blockIdx.x, tid = threadIdx.x;
  if (b < 2048)       { size_t i = ((size_t)b * 256 + tid) * 8;          cvt8(x,    xb,    i, f32); }
  else if (b < 2560)  { size_t i = ((size_t)(b - 2048) * 256 + tid) * 8; cvt8(wqa,  wqab,  i, f32); }
  else if (b < 3136)  { size_t i = ((size_t)(b - 2560) * 256 + tid) * 8; cvt8(wkva, wkvab, i, f32); }
  else {
    for (int i = tid; i < 512; i += 256) qabb[i]  = __float2bfloat16(rdv(qab,  i, f32));
    for (int i = tid; i < 576; i += 256) kvabb[i] = __float2bfloat16(rdv(kvab, i, f32));
  }
}

// convert wq_b (768 blks), wkv_b (1024), biases (2). Grid 1794.
__global__ __launch_bounds__(256) void convert_in2(
    const void* __restrict__ wqb, const void* __restrict__ wkvb,
    const void* __restrict__ qbb, const void* __restrict__ kvbb,
    bf16* __restrict__ wqbb, bf16* __restrict__ wkvbb,
    bf16* __restrict__ qbbb, bf16* __restrict__ kvbbb,
    const int* __restrict__ flagp)
{
  const int f32 = flagp[0];
  const int b = blockIdx.x, tid = threadIdx.x;
  if (b < 768)        { size_t i = ((size_t)b * 256 + tid) * 8;          cvt8(wqb,  wqbb,  i, f32); }
  else if (b < 1792)  { size_t i = ((size_t)(b - 768) * 256 + tid) * 8;  cvt8(wkvb, wkvbb, i, f32); }
  else if (b == 1792) { for (int i = tid; i < 3072; i += 256) qbbb[i]  = __float2bfloat16(rdv(qbb,  i, f32)); }
  else                { for (int i = tid; i < 4096; i += 256) kvbbb[i] = __float2bfloat16(rdv(kvbb, i, f32)); }
}

// convert wo (2048 blks) + wo bias (1 blk). Grid 2049. (ws >= 56MB tier)
__global__ __launch_bounds__(256) void convert_wo(
    const void* __restrict__ wo, const void* __restrict__ wob_in,
    bf16* __restrict__ wo16, bf16* __restrict__ wob16,
    const int* __restrict__ flagp)
{
  const int f32 = flagp[0];
  const int b = blockIdx.x, tid = threadIdx.x;
  if (b < 2048) { size_t i = ((size_t)b * 256 + tid) * 8; cvt8(wo, wo16, i, f32); }
  else { for (int i = tid; i < 2048; i += 256) wob16[i] = __float2bfloat16(rdv(wob_in, i, f32)); }
}

// ---- ALL conversions in ONE dispatch (ws >= 64MB tier): replaces
// detect_dtype + convert_in1 + convert_wo + convert_in2 (4 dispatches -> 1).
// Each block self-detects dtype from the SAME first 1KB of x (L2-broadcast,
// identical criterion/result as detect_dtype); block 3136 publishes flag for
// the downstream kernels (norms/rope_vt/reduce_out). Grid 6980. ------------
__global__ __launch_bounds__(256) void convert_all(
    const void* __restrict__ x,
    const void* __restrict__ wqa, const void* __restrict__ wkva,
    const void* __restrict__ qab, const void* __restrict__ kvab,
    const void* __restrict__ wqb, const void* __restrict__ wkvb,
    const void* __restrict__ qbb, const void* __restrict__ kvbb,
    const void* __restrict__ wo, const void* __restrict__ wob_in,
    bf16* __restrict__ xb, bf16* __restrict__ wqab, bf16* __restrict__ wkvab,
    bf16* __restrict__ qabb, bf16* __restrict__ kvabb,
    bf16* __restrict__ wqbb, bf16* __restrict__ wkvbb,
    bf16* __restrict__ qbbb, bf16* __restrict__ kvbbb,
    bf16* __restrict__ wo16, bf16* __restrict__ wob16,
    int* __restrict__ flag)
{
  __shared__ int red[4];
  const int b = blockIdx.x, tid = threadIdx.x;
  const int f32 = detect_exponents((const unsigned short*)x, tid, red);
  if (b < 2048)       { size_t i = ((size_t)b * 256 + tid) * 8;          cvt8(x,    xb,    i, f32); }
  else if (b < 2560)  { size_t i = ((size_t)(b - 2048) * 256 + tid) * 8; cvt8(wqa,  wqab,  i, f32); }
  else if (b < 3136)  { size_t i = ((size_t)(b - 2560) * 256 + tid) * 8; cvt8(wkva, wkvab, i, f32); }
  else if (b == 3136) {
    for (int i = tid; i < 512; i += 256) qabb[i]  = __float2bfloat16(rdv(qab,  i, f32));
    for (int i = tid; i < 576; i += 256) kvabb[i] = __float2bfloat16(rdv(kvab, i, f32));
    if (tid == 0) flag[0] = f32;
  }
  else if (b < 5185)  { size_t i = ((size_t)(b - 3137) * 256 + tid) * 8; cvt8(wo, wo16, i, f32); }
  else if (b == 5185) { for (int i = tid; i < 2048; i += 256) wob16[i] = __float2bfloat16(rdv(wob_in, i, f32)); }
  else if (b < 5954)  { size_t i = ((size_t)(b - 5186) * 256 + tid) * 8; cvt8(wqb,  wqbb,  i, f32); }
  else if (b < 6978)  { size_t i = ((size_t)(b - 5954) * 256 + tid) * 8; cvt8(wkvb, wkvbb, i, f32); }
  else if (b == 6978) { for (int i = tid; i < 3072; i += 256) qbbb[i]  = __float2bfloat16(rdv(qbb,  i, f32)); }
  else                { for (int i = tid; i < 4096; i += 256) kvbbb[i] = __float2bfloat16(rdv(kvbb, i, f32)); }
}

// ---------------- GEMM 128x128 body (round-7 logic + kbeg/kend/addbias) -----
template<int OMODE, bool A_DYN>
__device__ __forceinline__ void gemm128_body(
    const void* __restrict__ A, const void* __restrict__ W,
    const void* __restrict__ bias, void* __restrict__ Cout,
    int M, int N, int K, int f32in, int bx, int by,
    int kbeg, int kend, int addbias)
{
  __shared__ int4 As4[128 * 4];
  __shared__ int4 Bs4[128 * 4];
  const int tid = threadIdx.x, lane = tid & 63, wave = tid >> 6;
  const int grp = lane >> 4, l16 = lane & 15;
  const int m0 = bx * 128, n0 = by * 128;
  const int wm = (wave & 1) * 64, wn = (wave >> 1) * 64;
  float4x acc[4][4] = {};
  for (int k0 = kbeg; k0 < kend; k0 += 32) {
    if (!f32in) {
#pragma unroll
      for (int j = 0; j < 2; j++) {
        int row = wave * 32 + j * 16 + (lane >> 2);
        int cs = (lane & 3) ^ ((row >> 1) & 3);
        gload16((const bf16*)A + (size_t)(m0 + row) * K + k0 + cs * 8,
                &As4[(wave * 32 + j * 16) * 4]);
        gload16((const bf16*)W + (size_t)(n0 + row) * K + k0 + cs * 8,
                &Bs4[(wave * 32 + j * 16) * 4]);
      }
    } else {
#pragma unroll
      for (int i = 0; i < 2; i++) {
        int ch = tid + i * 256;
        int row = ch >> 2, c = ch & 3;
        int cs = c ^ ((row >> 1) & 3);
        size_t aoff = (size_t)(m0 + row) * K + k0 + cs * 8;
        size_t boff = (size_t)(n0 + row) * K + k0 + cs * 8;
        As4[row * 4 + c] = A_DYN ? pack8((const float*)A + aoff)
                                 : *(const int4*)((const bf16*)A + aoff);
        Bs4[row * 4 + c] = pack8((const float*)W + boff);
      }
    }
    __syncthreads();
    short8x af[4], bfr[4];
#pragma unroll
    for (int i = 0; i < 4; i++) {
      int ra = wm + i * 16 + l16;
      int rb = wn + i * 16 + l16;
      af[i]  = *(const short8x*)&As4[ra * 4 + (grp ^ ((ra >> 1) & 3))];
      bfr[i] = *(const short8x*)&Bs4[rb * 4 + (grp ^ ((rb >> 1) & 3))];
    }
#pragma unroll
    for (int i = 0; i < 4; i++)
#pragma unroll
      for (int j = 0; j < 4; j++)
        acc[i][j] = __builtin_amdgcn_mfma_f32_16x16x32_bf16(af[i], bfr[j], acc[i][j], 0, 0, 0);
    __syncthreads();
  }
#pragma unroll
  for (int j = 0; j < 4; j++) {
    int gn = n0 + wn + j * 16 + l16;
    float bv = addbias ? rdv(bias, gn, f32in) : 0.0f;
#pragma unroll
    for (int i = 0; i < 4; i++) {
      int gm0 = m0 + wm + i * 16 + grp * 4;
#pragma unroll
      for (int r = 0; r < 4; r++) {
        float v = acc[i][j][r] + bv;
        size_t idx = (size_t)(gm0 + r) * N + gn;
        if (OMODE == 0)      ((float*)Cout)[idx] = v;
        else if (OMODE == 1) ((bf16*)Cout)[idx] = __float2bfloat16(v);
        else {
          if (f32in) ((float*)Cout)[idx] = v;
          else       ((bf16*)Cout)[idx] = __float2bfloat16(v);
        }
      }
    }
  }
}

// q_b and kv_b in one dispatch (bf16 fast path: weights pre-converted):
// z=0 -> (qn,wq_b)->qbuf N=3072 (24 tiles); z=1 -> (kvn,wkv_b)->kvb N=4096.
__global__ __launch_bounds__(256) void gemmB_dual(
    const void* __restrict__ A0, const void* __restrict__ A1,
    const void* __restrict__ W0, const void* __restrict__ W1,
    const void* __restrict__ b0, const void* __restrict__ b1,
    void* __restrict__ C0, void* __restrict__ C1)
{
  const int z = blockIdx.z;
  if (z == 0 && blockIdx.y >= 24) return;
  const void* A = z ? A1 : A0;
  const void* W = z ? W1 : W0;
  const void* bias = z ? b1 : b0;
  void* C = z ? C1 : C0;
  const int N = z ? 4096 : 3072;
  gemm128_body<1, false>(A, W, bias, C, 2048, N, 512, 0,
                         blockIdx.x, blockIdx.y, 0, 512, 1);
}

// wo split-K=2, fp32-W fallback path (when ws lacks the bf16-wo region)
__global__ __launch_bounds__(256) void gemmWo_sk(
    const void* __restrict__ A, const void* __restrict__ W,
    const void* __restrict__ bias, float* __restrict__ part,
    const int* __restrict__ flagp)
{
  const int z = blockIdx.z;
  gemm128_body<0, false>(A, W, bias, part + (size_t)z * 2048 * 2048,
                         2048, 2048, 2048, flagp[0],
                         blockIdx.x, blockIdx.y, z * 1024, z * 1024 + 1024, z == 0);
}

// wo split-K=2, bf16 fast path (weights pre-converted)
__global__ __launch_bounds__(256) void gemmWo_sk_bf(
    const void* __restrict__ A, const void* __restrict__ W,
    const void* __restrict__ bias, float* __restrict__ part)
{
  const int z = blockIdx.z;
  gemm128_body<0, false>(A, W, bias, part + (size_t)z * 2048 * 2048,
                         2048, 2048, 2048, 0,
                         blockIdx.x, blockIdx.y, z * 1024, z * 1024 + 1024, z == 0);
}

// reduce: out = part0 + part1 (bias already in part0); out dtype per flag
__global__ __launch_bounds__(256) void reduce_out(
    const float* __restrict__ p0, const float* __restrict__ p1,
    void* __restrict__ out, const int* __restrict__ flagp)
{
  const int f32in = flagp[0];
  size_t i = ((size_t)blockIdx.x * 256 + threadIdx.x) * 4;
  float4 a = *(const float4*)(p0 + i);
  float4 b = *(const float4*)(p1 + i);
  a.x += b.x; a.y += b.y; a.z += b.z; a.w += b.w;
  if (f32in) {
    *(float4*)((float*)out + i) = a;
  } else {
    unsigned short h[4];
    bf16 t0 = __float2bfloat16(a.x); __builtin_memcpy(&h[0], &t0, 2);
    bf16 t1 = __float2bfloat16(a.y); __builtin_memcpy(&h[1], &t1, 2);
    bf16 t2 = __float2bfloat16(a.z); __builtin_memcpy(&h[2], &t2, 2);
    bf16 t3 = __float2bfloat16(a.w); __builtin_memcpy(&h[3], &t3, 2);
    int2 v;
    v.x = (int)((unsigned)h[0] | ((unsigned)h[1] << 16));
    v.y = (int)((unsigned)h[2] | ((unsigned)h[3] << 16));
    *(int2*)((bf16*)out + i) = v;
  }
}

// ---------------- GEMM 64x64 body (round-7 logic + kbeg/kend/addbias) -------
template<int OMODE, bool A_DYN>
__device__ __forceinline__ void gemm64_body(
    const void* __restrict__ A, const void* __restrict__ W,
    const void* __restrict__ bias, void* __restrict__ Cout,
    int M, int N, int K, int f32in, int bx, int by,
    int kbeg, int kend, int addbias)
{
  __shared__ int4 As4[64 * 4];
  __shared__ int4 Bs4[64 * 4];
  const int tid = threadIdx.x, lane = tid & 63, wave = tid >> 6;
  const int grp = lane >> 4, l16 = lane & 15;
  const int m0 = bx * 64, n0 = by * 64;
  const int wm = (wave & 1) * 32, wn = (wave >> 1) * 32;
  float4x acc[2][2] = {};
  for (int k0 = kbeg; k0 < kend; k0 += 32) {
    if (!f32in) {
      int row = wave * 16 + (lane >> 2);
      int cs = (lane & 3) ^ ((row >> 1) & 3);
      gload16((const bf16*)A + (size_t)(m0 + row) * K + k0 + cs * 8,
              &As4[wave * 16 * 4]);
      gload16((const bf16*)W + (size_t)(n0 + row) * K + k0 + cs * 8,
              &Bs4[wave * 16 * 4]);
    } else {
      int row = tid >> 2, c = tid & 3;
      int cs = c ^ ((row >> 1) & 3);
      size_t aoff = (size_t)(m0 + row) * K + k0 + cs * 8;
      size_t boff = (size_t)(n0 + row) * K + k0 + cs * 8;
      As4[row * 4 + c] = A_DYN ? pack8((const float*)A + aoff)
                               : *(const int4*)((const bf16*)A + aoff);
      Bs4[row * 4 + c] = pack8((const float*)W + boff);
    }
    __syncthreads();
    short8x af[2], bfr[2];
#pragma unroll
    for (int i = 0; i < 2; i++) {
      int ra = wm + i * 16 + l16;
      int rb = wn + i * 16 + l16;
      af[i]  = *(const short8x*)&As4[ra * 4 + (grp ^ ((ra >> 1) & 3))];
      bfr[i] = *(const short8x*)&Bs4[rb * 4 + (grp ^ ((rb >> 1) & 3))];
    }
#pragma unroll
    for (int i = 0; i < 2; i++)
#pragma unroll
      for (int j = 0; j < 2; j++)
        acc[i][j] = __builtin_amdgcn_mfma_f32_16x16x32_bf16(af[i], bfr[j], acc[i][j], 0, 0, 0);
    __syncthreads();
  }
#pragma unroll
  for (int j = 0; j < 2; j++) {
    int gn = n0 + wn + j * 16 + l16;
    float bv = addbias ? rdv(bias, gn, f32in) : 0.0f;
#pragma unroll
    for (int i = 0; i < 2; i++) {
      int gm0 = m0 + wm + i * 16 + grp * 4;
#pragma unroll
      for (int r = 0; r < 4; r++) {
        float v = acc[i][j][r] + bv;
        size_t idx = (size_t)(gm0 + r) * N + gn;
        if (OMODE == 0)      ((float*)Cout)[idx] = v;
        else if (OMODE == 1) ((bf16*)Cout)[idx] = __float2bfloat16(v);
        else {
          if (f32in) ((float*)Cout)[idx] = v;
          else       ((bf16*)Cout)[idx] = __float2bfloat16(v);
        }
      }
    }
  }
}

// q_a/kv_a projections on pre-converted bf16 inputs (fast gload16 path),
// split-K=2, fused: grid (32,9,4); z = (mat<<1)|khalf.
__global__ __launch_bounds__(256) void gemmA_sk(
    const void* __restrict__ A,
    const void* __restrict__ W0, const void* __restrict__ W1,
    const void* __restrict__ b0, const void* __restrict__ b1,
    float* __restrict__ C0, float* __restrict__ C1)
{
  const int z = blockIdx.z;
  const int mat = z >> 1, kh = z & 1;
  const int N = mat ? 576 : 512;
  if (blockIdx.y * 64 >= N) return;
  const void* W = mat ? W1 : W0;
  const void* bias = mat ? b1 : b0;
  float* C = (mat ? C1 : C0) + (size_t)kh * 2048 * N;
  gemm64_body<0, false>(A, W, bias, C, 2048, N, 2048, 0,
                        blockIdx.x, blockIdx.y,
                        kh * 1024, kh * 1024 + 1024, kh == 0);
}

// ------ merged norms w/ fused split-K reduce: b<2048 -> q; else kv ----------
__global__ __launch_bounds__(256) void norms_merged(
    const float* __restrict__ q_a0, const float* __restrict__ q_a1,
    const float* __restrict__ kv_a0, const float* __restrict__ kv_a1,
    const void* __restrict__ qw, const void* __restrict__ kvw,
    const void* __restrict__ cosb, const void* __restrict__ sinb,
    bf16* __restrict__ qn, bf16* __restrict__ kvn, bf16* __restrict__ kpe,
    const int* __restrict__ flagp)
{
  const int f32in = flagp[0];
  const int b = blockIdx.x, tid = threadIdx.x;
  __shared__ float red[4];
  if (b < 2048) {
    const int s = b;
    size_t base = (size_t)s * 512;
    float v0 = q_a0[base + tid] + q_a1[base + tid];
    float v1 = q_a0[base + tid + 256] + q_a1[base + tid + 256];
    float ss = v0 * v0 + v1 * v1;
#pragma unroll
    for (int off = 1; off < 64; off <<= 1) ss += __shfl_xor(ss, off);
    if ((tid & 63) == 0) red[tid >> 6] = ss;
    __syncthreads();
    float tot = red[0] + red[1] + red[2] + red[3];
    float scale = rsqrtf(tot * (1.0f / 512.0f) + EPS_F);
    qn[base + tid]       = __float2bfloat16(v0 * scale * rdv(qw, tid, f32in));
    qn[base + tid + 256] = __float2bfloat16(v1 * scale * rdv(qw, tid + 256, f32in));
  } else {
    const int s = b - 2048;
    size_t base = (size_t)s * 576;
    float v0 = kv_a0[base + tid] + kv_a1[base + tid];
    float v1 = kv_a0[base + tid + 256] + kv_a1[base + tid + 256];
    float ss = v0 * v0 + v1 * v1;
#pragma unroll
    for (int off = 1; off < 64; off <<= 1) ss += __shfl_xor(ss, off);
    if ((tid & 63) == 0) red[tid >> 6] = ss;
    __syncthreads();
    float tot = red[0] + red[1] + red[2] + red[3];
    float scale = rsqrtf(tot * (1.0f / 512.0f) + EPS_F);
    kvn[(size_t)s * 512 + tid]       = __float2bfloat16(v0 * scale * rdv(kvw, tid, f32in));
    kvn[(size_t)s * 512 + tid + 256] = __float2bfloat16(v1 * scale * rdv(kvw, tid + 256, f32in));
    if (tid < 32) {
      float x0 = kv_a0[base + 512 + 2 * tid] + kv_a1[base + 512 + 2 * tid];
      float x1 = kv_a0[base + 512 + 2 * tid + 1] + kv_a1[base + 512 + 2 * tid + 1];
      float c  = rdv(cosb, (size_t)s * 32 + tid, f32in);
      float sn = rdv(sinb, (size_t)s * 32 + tid, f32in);
      kpe[s * 64 + 2 * tid]     = __float2bfloat16(x0 * c - x1 * sn);
      kpe[s * 64 + 2 * tid + 1] = __float2bfloat16(x0 * sn + x1 * c);
    }
  }
}

// ------ merged rope_q (b<2048) + build_vt (b>=2048, 512 blocks) -------------
__global__ __launch_bounds__(256) void rope_vt_merged(
    bf16* __restrict__ q, const void* __restrict__ cosb,
    const void* __restrict__ sinb, const bf16* __restrict__ kvb,
    bf16* __restrict__ Vt, const int* __restrict__ flagp)
{
  const int b = blockIdx.x, tid = threadIdx.x;
  __shared__ __align__(16) bf16 tile[64][136];
  if (b < 2048) {
    const int f32in = flagp[0];
    const int s = b;
#pragma unroll
    for (int it = 0; it < 2; it++) {
      int p = tid + it * 256;
      int hh = p >> 5, jj = p & 31;
      bf16* src = q + (size_t)s * 3072 + hh * 192 + 128 + 2 * jj;
      float x0 = __bfloat162float(src[0]);
      float x1 = __bfloat162float(src[1]);
      float c  = rdv(cosb, (size_t)s * 32 + jj, f32in);
      float sn = rdv(sinb, (size_t)s * 32 + jj, f32in);
      src[0] = __float2bfloat16(x0 * c - x1 * sn);
      src[1] = __float2bfloat16(x0 * sn + x1 * c);
    }
  } else {
    const int hb = b - 2048;                 // 0..511
    const int h = hb & 15;
    const int t0 = (hb >> 4) * 64;
#pragma unroll
    for (int i = 0; i < 4; i++) {
      int chunk = tid + i * 256;
      int row = chunk >> 4;
      int c8 = (chunk & 15) * 8;
      *(int4*)&tile[row][c8] =
          *(const int4*)(kvb + (size_t)(t0 + row) * 4096 + h * 256 + 128 + c8);
    }
    __syncthreads();
#pragma unroll
    for (int i = 0; i < 32; i++) {
      int idx = tid + i * 256;
      int d = idx >> 6;
      int t = idx & 63;
      Vt[((size_t)h * 128 + d) * 2048 + t0 + t] = tile[t][d];
    }
  }
}

// ---------------- flash attention (round-0 exact — verified 81.5-83 µs in
// r0/r5/r7; all restructurings regressed and are reverted. attn is closed). --
__global__ __launch_bounds__(256) void attn_kernel(
    const bf16* __restrict__ Q, const bf16* __restrict__ kvb,
    const bf16* __restrict__ kpe, const bf16* __restrict__ Vt,
    bf16* __restrict__ Out)
{
  __shared__ __align__(16) bf16 Ks[64 * 200];
  __shared__ __align__(16) bf16 Vs[128 * 72];
  __shared__ __align__(16) bf16 plds[4][16 * 68];
  const int b = blockIdx.x;
  const int h = b & 15;
  const int tt = (b >> 4) & 15;
  const int q0 = ((b >> 8) ? (31 - tt) : tt) * 64;
  const int tid = threadIdx.x;
  const int wave = tid >> 6;
  const int lane = tid & 63;
  const int grp = lane >> 4, l16 = lane & 15;
  const int qrt = q0 + wave * 16;
  const bf16* Qbase = Q + (size_t)(qrt + l16) * 3072 + h * 192;
  short8x qf[6];
#pragma unroll
  for (int c = 0; c < 6; c++)
    qf[c] = *(const short8x*)(Qbase + c * 32 + grp * 8);
  float m_run[4], l_run[4];
  float4x o_acc[8] = {};
#pragma unroll
  for (int r = 0; r < 4; r++) { m_run[r] = -__builtin_inff(); l_run[r] = 0.f; }
  bf16* pl = &plds[wave][0];
  for (int t0 = 0; t0 <= q0; t0 += 64) {
#pragma unroll
    for (int i = 0; i < 4; i++) {
      int ch = tid + i * 256;
      int row = ch >> 4, c = ch & 15;
      *(int4*)&Ks[row * 200 + c * 8] =
          *(const int4*)(kvb + (size_t)(t0 + row) * 4096 + h * 256 + c * 8);
    }
#pragma unroll
    for (int i = 0; i < 2; i++) {
      int ch = tid + i * 256;
      int row = ch >> 3, c = ch & 7;
      *(int4*)&Ks[row * 200 + 128 + c * 8] =
          *(const int4*)(kpe + (size_t)(t0 + row) * 64 + c * 8);
    }
#pragma unroll
    for (int i = 0; i < 4; i++) {
      int ch = tid + i * 256;
      int row = ch >> 3, c = ch & 7;
      *(int4*)&Vs[row * 72 + c * 8] =
          *(const int4*)(Vt + ((size_t)h * 128 + row) * 2048 + t0 + c * 8);
    }
    __syncthreads();
    float4x sacc[4] = {};
#pragma unroll
    for (int n = 0; n < 4; n++) {
      const bf16* Kb = &Ks[(n * 16 + l16) * 200 + grp * 8];
#pragma unroll
      for (int c = 0; c < 6; c++) {
        short8x kf = *(const short8x*)(Kb + c * 32);
        sacc[n] = __builtin_amdgcn_mfma_f32_16x16x32_bf16(qf[c], kf, sacc[n], 0, 0, 0);
      }
    }
    float pv[4][4], alpha[4];
#pragma unroll
    for (int r = 0; r < 4; r++) {
      const int s_row = qrt + grp * 4 + r;
      float p0[4];
      float mx = -__builtin_inff();
#pragma unroll
      for (int n = 0; n < 4; n++) {
        int t = t0 + n * 16 + l16;
        float v = sacc[n][r] * SCALE_F;
        v = (t > s_row) ? -1.0e9f : v;
        p0[n] = v;
        mx = fmaxf(mx, v);
      }
      mx = fmaxf(mx, __shfl_xor(mx, 1));
      mx = fmaxf(mx, __shfl_xor(mx, 2));
      mx = fmaxf(mx, __shfl_xor(mx, 4));
      mx = fmaxf(mx, __shfl_xor(mx, 8));
      float m_new = fmaxf(m_run[r], mx);
      float a = __expf(m_run[r] - m_new);
      m_run[r] = m_new;
      float sum = 0.f;
#pragma unroll
      for (int n = 0; n < 4; n++) {
        float e = __expf(p0[n] - m_new);
        pv[n][r] = e;
        sum += e;
      }
      sum += __shfl_xor(sum, 1);
      sum += __shfl_xor(sum, 2);
      sum += __shfl_xor(sum, 4);
      sum += __shfl_xor(sum, 8);
      l_run[r] = l_run[r] * a + sum;
      alpha[r] = a;
    }
#pragma unroll
    for (int n = 0; n < 8; n++)
#pragma unroll
      for (int r = 0; r < 4; r++)
        o_acc[n][r] *= alpha[r];
#pragma unroll
    for (int n = 0; n < 4; n++)
#pragma unroll
      for (int r = 0; r < 4; r++)
        pl[(grp * 4 + r) * 68 + n * 16 + l16] = __float2bfloat16(pv[n][r]);
#pragma unroll
    for (int c = 0; c < 2; c++) {
      union { short4x h4[2]; short8x v8; } pk;
      const bf16* pp = pl + l16 * 68 + c * 32 + grp * 8;
      pk.h4[0] = *(const short4x*)(pp);
      pk.h4[1] = *(const short4x*)(pp + 4);
#pragma unroll
      for (int n = 0; n < 8; n++) {
        short8x vf = *(const short8x*)&Vs[(size_t)(n * 16 + l16) * 72 + c * 32 + grp * 8];
        o_acc[n] = __builtin_amdgcn_mfma_f32_16x16x32_bf16(pk.v8, vf, o_acc[n], 0, 0, 0);
      }
    }
    __syncthreads();
  }
  float inv[4];
#pragma unroll
  for (int r = 0; r < 4; r++) inv[r] = 1.0f / l_run[r];
#pragma unroll
  for (int n = 0; n < 8; n++)
#pragma unroll
    for (int r = 0; r < 4; r++) {
      int s_row = qrt + grp * 4 + r;
      Out[(size_t)s_row * 2048 + h * 128 + n * 16 + l16] =
          __float2bfloat16(o_acc[n][r] * inv[r]);
    }
}

extern "C" void kernel_launch(void* const* d_in, const int* in_sizes, int n_in,
                              void* d_out, int out_size, void* d_ws, size_t ws_size,
                              hipStream_t stream) {
  const void* x        = d_in[0];
  const void* fcos     = d_in[2];
  const void* fsin     = d_in[3];
  const void* wq_a_w   = d_in[5];
  const void* wq_a_b   = d_in[6];
  const void* q_norm_w = d_in[7];
  const void* wq_b_w   = d_in[8];
  const void* wq_b_b   = d_in[9];
  const void* wkv_a_w  = d_in[10];
  const void* wkv_a_b  = d_in[11];
  const void* kv_norm_w= d_in[12];
  const void* wkv_b_w  = d_in[13];
  const void* wkv_b_b  = d_in[14];
  const void* wo_w     = d_in[15];
  const void* wo_b     = d_in[16];

  const size_t KB = 1024, MB = 1024 * 1024;
  if (ws_size < 46 * MB) {   // diagnostic: absmax ~1000 => ws too small
    sentinel_kernel<<<(out_size + 255) / 256, 256, 0, stream>>>((bf16*)d_out, out_size);
    return;
  }
  char* ws = (char*)d_ws;
  // Region plan, peak 44.5 MB (46 MB guard). Persistent: kpe[0,0.25M)
  //   flag@0.25M qbuf[0.5,12.5) kvb[12.5,28.5) Vt[28.5,36.5) attnout[36.5,44.5).
  // Transients (time-disjoint with their hosts):
  //   kv_a0/1 [0.5,9.5)   in qbuf    (dead before gemmB writes qbuf)
  //   q_a0/1  [36.5,44.5) in attnout (dead before convert_in2 [mid tier])
  //   xb/wqab/wkvab/biasA [12.5,25.1) in kvb (dead before gemmB writes kvb)
  //   wqbb/wkvbb/biasB [36.5,43.8) in attnout [mid tier only]
  //   qn/kvn  [28.5,32.5) in Vt      (dead before rope_vt writes Vt)
  //   wpart   [0.5,32.5)  in qbuf+kvb+Vt (all dead after attn)
  // TIER ws>=56MB ("wofast"): wo16 [46,54), wob16 @54.5 — bf16 Wo GEMM.
  // TIER ws>=64MB ("bigws"): additionally wqbb [56,59), wkvbb [59,63),
  //   qbbb @63.0, kvbbb @63.0625 — ALL conversions hoisted into ONE up-front
  //   convert_all dispatch (replaces detect+conv1+conv_wo+conv2; 4 -> 1).
  bf16*  kpe    = (bf16*)(ws);
  int*   flag   = (int*)(ws + 256 * KB);
  bf16*  qbuf   = (bf16*)(ws + 512 * KB);
  bf16*  kvb    = (bf16*)(ws + 12 * MB + 512 * KB);
  bf16*  Vt     = (bf16*)(ws + 28 * MB + 512 * KB);
  bf16*  attnout= (bf16*)(ws + 36 * MB + 512 * KB);
  float* kv_a0  = (float*)(ws + 512 * KB);
  float* kv_a1  = (float*)(ws + 5 * MB);
  float* q_a0   = (float*)(ws + 36 * MB + 512 * KB);
  float* q_a1   = (float*)(ws + 40 * MB + 512 * KB);
  bf16*  qn     = (bf16*)(ws + 28 * MB + 512 * KB);
  bf16*  kvn    = (bf16*)(ws + 30 * MB + 512 * KB);
  float* wpart  = (float*)(ws + 512 * KB);
  // bf16 conversion targets (shared by all tiers)
  bf16*  xb     = (bf16*)(ws + 12 * MB + 512 * KB);   // 8MB   [12.5,20.5)
  bf16*  wqab   = (bf16*)(ws + 20 * MB + 512 * KB);   // 2MB   [20.5,22.5)
  bf16*  wkvab  = (bf16*)(ws + 22 * MB + 512 * KB);   // 2.25M [22.5,24.75)
  bf16*  qabb   = (bf16*)(ws + 25 * MB);              // 1KB
  bf16*  kvabb  = (bf16*)(ws + 25 * MB + 64 * KB);    // 1.2KB
  // mid-tier B-stage targets (attnout region, written after norms)
  bf16*  wqbb_m = (bf16*)(ws + 36 * MB + 512 * KB);   // 3MB   [36.5,39.5)
  bf16*  wkvbb_m= (bf16*)(ws + 39 * MB + 512 * KB);   // 4MB   [39.5,43.5)
  bf16*  qbbb_m = (bf16*)(ws + 43 * MB + 512 * KB);   // 6KB
  bf16*  kvbbb_m= (bf16*)(ws + 43 * MB + 768 * KB);   // 8KB
  // wofast region
  bf16*  wo16   = (bf16*)(ws + 46 * MB);              // 8MB   [46,54)
  bf16*  wob16  = (bf16*)(ws + 54 * MB + 512 * KB);   // 4KB
  // bigws B-stage targets (persistent, no conflict with q_a)
  bf16*  wqbb_b = (bf16*)(ws + 56 * MB);              // 3MB   [56,59)
  bf16*  wkvbb_b= (bf16*)(ws + 59 * MB);              // 4MB   [59,63)
  bf16*  qbbb_b = (bf16*)(ws + 63 * MB);              // 6KB
  bf16*  kvbbb_b= (bf16*)(ws + 63 * MB + 64 * KB);    // 8KB

  const bool wofast = (ws_size >= 56 * MB);
  const bool bigws  = (ws_size >= 64 * MB);

  dim3 blk(256);
  if (bigws) {
    // ONE up-front conversion dispatch (self-detecting; publishes flag)
    convert_all<<<6980, blk, 0, stream>>>(
        x, wq_a_w, wkv_a_w, wq_a_b, wkv_a_b, wq_b_w, wkv_b_w, wq_b_b, wkv_b_b,
        wo_w, wo_b,
        xb, wqab, wkvab, qabb, kvabb, wqbb_b, wkvbb_b, qbbb_b, kvbbb_b,
        wo16, wob16, flag);
    gemmA_sk<<<dim3(32, 9, 4), blk, 0, stream>>>(
        xb, wqab, wkvab, qabb, kvabb, q_a0, kv_a0);
    norms_merged<<<4096, blk, 0, stream>>>(
        q_a0, q_a1, kv_a0, kv_a1, q_norm_w, kv_norm_w, fcos, fsin,
        qn, kvn, kpe, flag);
    gemmB_dual<<<dim3(16, 32, 2), blk, 0, stream>>>(
        qn, kvn, wqbb_b, wkvbb_b, qbbb_b, kvbbb_b, qbuf, kvb);
    rope_vt_merged<<<2560, blk, 0, stream>>>(qbuf, fcos, fsin, kvb, Vt, flag);
    attn_kernel<<<dim3(512), blk, 0, stream>>>(qbuf, kvb, kpe, Vt, attnout);
    gemmWo_sk_bf<<<dim3(16, 16, 2), blk, 0, stream>>>(attnout, wo16, wob16, wpart);
    reduce_out<<<4096, blk, 0, stream>>>(wpart, wpart + (size_t)2048 * 2048, d_out, flag);
  } else {
    detect_dtype<<<1, blk, 0, stream>>>((const unsigned short*)x, flag);
    convert_in1<<<3137, blk, 0, stream>>>(
        x, wq_a_w, wkv_a_w, wq_a_b, wkv_a_b, xb, wqab, wkvab, qabb, kvabb, flag);
    if (wofast)
      convert_wo<<<2049, blk, 0, stream>>>(wo_w, wo_b, wo16, wob16, flag);
    gemmA_sk<<<dim3(32, 9, 4), blk, 0, stream>>>(
        xb, wqab, wkvab, qabb, kvabb, q_a0, kv_a0);
    norms_merged<<<4096, blk, 0, stream>>>(
        q_a0, q_a1, kv_a0, kv_a1, q_norm_w, kv_norm_w, fcos, fsin,
        qn, kvn, kpe, flag);
    convert_in2<<<1794, blk, 0, stream>>>(
        wq_b_w, wkv_b_w, wq_b_b, wkv_b_b, wqbb_m, wkvbb_m, qbbb_m, kvbbb_m, flag);
    gemmB_dual<<<dim3(16, 32, 2), blk, 0, stream>>>(
        qn, kvn, wqbb_m, wkvbb_m, qbbb_m, kvbbb_m, qbuf, kvb);
    rope_vt_merged<<<2560, blk, 0, stream>>>(qbuf, fcos, fsin, kvb, Vt, flag);
    attn_kernel<<<dim3(512), blk, 0, stream>>>(qbuf, kvb, kpe, Vt, attnout);
    if (wofast)
      gemmWo_sk_bf<<<dim3(16, 16, 2), blk, 0, stream>>>(attnout, wo16, wob16, wpart);
    else
      gemmWo_sk<<<dim3(16, 16, 2), blk, 0, stream>>>(attnout, wo_w, wo_b, wpart, flag);
    reduce_out<<<4096, blk, 0, stream>>>(wpart, wpart + (size_t)2048 * 2048, d_out, flag);
  }
}